// Round 13
// baseline (178.795 us; speedup 1.0000x reference)
//
#include <hip/hip_runtime.h>

#define N_NODES 50000
#define N_EDGES 800000
#define F 128
#define HDIM 64
#define NE 3
#define NGRAPH 64
#define NC 3
#define BN_EPS 1e-5f
#define NBLK_A 200      // histogram/place blocks, 4000 edges each
#define NBUCK 196       // ceil(N_NODES/256) buckets of 256 nodes
#define NBLK_EXP 782    // ceil(N/64)
#define NBLK_GY 1563    // ceil(N/32)

typedef __attribute__((ext_vector_type(8))) short short8;
typedef __attribute__((ext_vector_type(4))) float f32x4;

__device__ inline unsigned short f2bf(float f) {
    unsigned int u = __float_as_uint(f);
    unsigned int r = (u + 0x7FFFu + ((u >> 16) & 1u)) >> 16;
    return (unsigned short)r;
}
__device__ inline float bf2f(unsigned short u) {
    return __uint_as_float(((unsigned int)u) << 16);
}

// ---------------- merged prep: W packs + gseg + bucket histogram + zero psum/pmax ----------------
__global__ __launch_bounds__(256) void k_prep(const float* __restrict__ Wexp,
        const float* __restrict__ gW1, const int* __restrict__ batch,
        const int* __restrict__ dst,
        unsigned short* __restrict__ wpack, unsigned short* __restrict__ gwpack,
        int* __restrict__ gstart, int* __restrict__ bh, float* __restrict__ zbase) {
    int b = blockIdx.x, tid = threadIdx.x;
    if (b < 12) {
        int t0 = b * 256 + tid;
        int f = t0 >> 6, l = t0 & 63;
        int e = f >> 4, t = (f >> 2) & 3, kk = f & 3;
        int h = t * 16 + (l & 15);
        int kbase = kk * 32 + (l >> 4) * 8;
        short8 o;
        #pragma unroll
        for (int j = 0; j < 8; ++j)
            o[j] = (short)f2bf(Wexp[e * (F * HDIM) + (kbase + j) * HDIM + h]);
        ((short8*)wpack)[f * 64 + l] = o;
    } else if (b == 12) {
        for (int t0 = tid; t0 < 8 * 64; t0 += 256) {
            int f = t0 >> 6, l = t0 & 63;
            int t = f >> 2, kk = f & 3;
            int h = t * 16 + (l & 15);
            int kbase = kk * 32 + (l >> 4) * 8;
            short8 o;
            #pragma unroll
            for (int j = 0; j < 8; ++j)
                o[j] = (short)f2bf(gW1[(kbase + j) * 32 + h]);
            ((short8*)gwpack)[f * 64 + l] = o;
        }
    } else if (b == 13) {
        int g = tid;
        if (g <= NGRAPH) {
            int lo = 0, hi = N_NODES;
            while (lo < hi) { int m = (lo + hi) >> 1; if (batch[m] < g) lo = m + 1; else hi = m; }
            gstart[g] = lo;
        }
    } else if (b < 14 + NBLK_A) {
        __shared__ int hist[256];
        hist[tid] = 0;
        __syncthreads();
        int base = (b - 14) * 4000;
        for (int i = tid; i < 4000; i += 256)
            atomicAdd(&hist[dst[base + i] >> 8], 1);
        __syncthreads();
        bh[(b - 14) * 256 + tid] = hist[tid];
    } else {
        int idx = (b - 14 - NBLK_A) * 256 + tid;   // zero psum(4096)+pmax(4096)
        if (idx < 8192) zbase[idx] = 0.f;
    }
}

// ---------------- CSR build, pass B: scan ----------------
__global__ __launch_bounds__(256) void k_bscan(int* __restrict__ bh, int* __restrict__ bucketbase,
                                               int* __restrict__ row_start) {
    int b = threadIdx.x;
    int sum = 0;
    #pragma unroll 4
    for (int k = 0; k < NBLK_A; ++k) {
        int v = bh[k * 256 + b];
        bh[k * 256 + b] = sum;
        sum += v;
    }
    int lane = b & 63, wid = b >> 6;
    __shared__ int wsums[4];
    int xsc = sum;
    #pragma unroll
    for (int off = 1; off < 64; off <<= 1) {
        int u = __shfl_up(xsc, off, 64);
        if (lane >= off) xsc += u;
    }
    if (lane == 63) wsums[wid] = xsc;
    __syncthreads();
    int woff = 0;
    for (int wq = 0; wq < wid; ++wq) woff += wsums[wq];
    int excl = woff + xsc - sum;
    bucketbase[b] = excl;
    if (b == 255) {
        bucketbase[256] = excl + sum;
        row_start[N_NODES] = excl + sum;
    }
}

// ---------------- CSR build, pass C: scatter packed (src<<8|dst&255) grouped by bucket ----------------
__global__ __launch_bounds__(256) void k_bplace(const int* __restrict__ ei, const int* __restrict__ bh,
        const int* __restrict__ bucketbase, int* __restrict__ pairs) {
    __shared__ int cur[256];
    int tid = threadIdx.x;
    cur[tid] = bucketbase[tid] + bh[blockIdx.x * 256 + tid];
    __syncthreads();
    int base = blockIdx.x * 4000;
    for (int i = tid; i < 4000; i += 256) {
        int e = base + i;
        int s = ei[e], d = ei[N_EDGES + e];
        int slot = atomicAdd(&cur[d >> 8], 1);
        pairs[slot] = (s << 8) | (d & 255);
    }
}

// ---------------- CSR build, pass D: per-bucket degrees, row_start, final placement ----------------
__global__ __launch_bounds__(256) void k_bfinal(const int* __restrict__ pairs,
        const int* __restrict__ bucketbase, int* __restrict__ row_start,
        float* __restrict__ deg_isqrt, int* __restrict__ csr_src) {
    __shared__ int deg[256];
    __shared__ int cur[256];
    __shared__ int wsums[4];
    int b = blockIdx.x, t = threadIdx.x;
    int beg = bucketbase[b], end = bucketbase[b + 1];
    deg[t] = 0;
    __syncthreads();
    for (int i = beg + t; i < end; i += 256)
        atomicAdd(&deg[pairs[i] & 255], 1);
    __syncthreads();
    int d = deg[t];
    int lane = t & 63, wid = t >> 6;
    int xsc = d;
    #pragma unroll
    for (int off = 1; off < 64; off <<= 1) {
        int u = __shfl_up(xsc, off, 64);
        if (lane >= off) xsc += u;
    }
    if (lane == 63) wsums[wid] = xsc;
    __syncthreads();
    int woff = 0;
    for (int wq = 0; wq < wid; ++wq) woff += wsums[wq];
    int rs = beg + woff + xsc - d;
    int node = b * 256 + t;
    if (node < N_NODES) {
        row_start[node] = rs;
        deg_isqrt[node] = rsqrtf((float)d + 1.0f);
    }
    cur[t] = rs;
    __syncthreads();
    for (int i = beg + t; i < end; i += 256) {
        int p = pairs[i];
        int slot = atomicAdd(&cur[p & 255], 1);
        csr_src[slot] = p >> 8;
    }
}

// ---------------- gate via MFMA + x' = x*isq bf16 side-output ----------------
__global__ __launch_bounds__(256) void k_gateM(const float* __restrict__ x,
        const float* __restrict__ deg_isqrt, const unsigned short* __restrict__ gwpack,
        const float* __restrict__ gb1, const float* __restrict__ gW2,
        const float* __restrict__ gb2, float* __restrict__ gate,
        unsigned short* __restrict__ xpb1) {
    int tid = threadIdx.x;
    int w = tid >> 6, l = tid & 63;
    int lo = l & 15, hi = l >> 4;
    int n0 = blockIdx.x * 64 + w * 16;
    int nlo = n0 + lo;
    bool vrow = nlo < N_NODES;
    int arow = vrow ? nlo : N_NODES - 1;
    float si = deg_isqrt[arow];
    short8 a[4];
    #pragma unroll
    for (int kk = 0; kk < 4; ++kk) {
        int c4 = (kk * 32 + hi * 8) >> 2;
        float4 v0 = ((const float4*)x)[(size_t)arow * 32 + c4];
        float4 v1 = ((const float4*)x)[(size_t)arow * 32 + c4 + 1];
        short8 t8;
        t8[0] = (short)f2bf(v0.x); t8[1] = (short)f2bf(v0.y);
        t8[2] = (short)f2bf(v0.z); t8[3] = (short)f2bf(v0.w);
        t8[4] = (short)f2bf(v1.x); t8[5] = (short)f2bf(v1.y);
        t8[6] = (short)f2bf(v1.z); t8[7] = (short)f2bf(v1.w);
        a[kk] = t8;
        if (vrow) {
            ushort4 o0, o1;
            o0.x = f2bf(v0.x * si); o0.y = f2bf(v0.y * si);
            o0.z = f2bf(v0.z * si); o0.w = f2bf(v0.w * si);
            o1.x = f2bf(v1.x * si); o1.y = f2bf(v1.y * si);
            o1.z = f2bf(v1.z * si); o1.w = f2bf(v1.w * si);
            ((ushort4*)xpb1)[(size_t)arow * 32 + c4]     = o0;
            ((ushort4*)xpb1)[(size_t)arow * 32 + c4 + 1] = o1;
        }
    }
    const short8* gw8 = (const short8*)gwpack;
    f32x4 acc0 = {0.f, 0.f, 0.f, 0.f}, acc1 = {0.f, 0.f, 0.f, 0.f};
    #pragma unroll
    for (int kk = 0; kk < 4; ++kk) {
        acc0 = __builtin_amdgcn_mfma_f32_16x16x32_bf16(a[kk], gw8[kk * 64 + l], acc0, 0, 0, 0);
        acc1 = __builtin_amdgcn_mfma_f32_16x16x32_bf16(a[kk], gw8[(4 + kk) * 64 + l], acc1, 0, 0, 0);
    }
    float b1a = gb1[lo], b1b = gb1[16 + lo];
    float w20[3], w21[3];
    #pragma unroll
    for (int e = 0; e < 3; ++e) { w20[e] = gW2[lo * 3 + e]; w21[e] = gW2[(16 + lo) * 3 + e]; }
    float bb0 = gb2[0], bb1 = gb2[1], bb2 = gb2[2];
    #pragma unroll
    for (int r = 0; r < 4; ++r) {
        float h0 = fmaxf(acc0[r] + b1a, 0.f);
        float h1 = fmaxf(acc1[r] + b1b, 0.f);
        float le[3];
        #pragma unroll
        for (int e = 0; e < 3; ++e) {
            float p = fmaf(h0, w20[e], h1 * w21[e]);
            p += __shfl_xor(p, 1, 64);
            p += __shfl_xor(p, 2, 64);
            p += __shfl_xor(p, 4, 64);
            p += __shfl_xor(p, 8, 64);
            le[e] = p;
        }
        le[0] += bb0; le[1] += bb1; le[2] += bb2;
        float m = fmaxf(le[0], fmaxf(le[1], le[2]));
        float e0 = __expf(le[0] - m), e1 = __expf(le[1] - m), e2 = __expf(le[2] - m);
        float inv = 1.f / (e0 + e1 + e2);
        int n = n0 + hi * 4 + r;
        if (n < N_NODES && lo < 3) {
            float gg = (lo == 0) ? e0 * inv : (lo == 1 ? e1 * inv : e2 * inv);
            gate[n * 3 + lo] = gg;
        }
    }
}

// ---------------- MERGED: stage-1 gather (bf16) -> LDS tile -> expert MFMA + bn1 partials ----------------
__global__ __launch_bounds__(256) void k_gx_exp(const int* __restrict__ csr_src,
        const int* __restrict__ row_start, const float* __restrict__ deg_isqrt,
        const unsigned short* __restrict__ xpb1,
        const unsigned short* __restrict__ wpack, const float* __restrict__ bexp,
        const float* __restrict__ gate, unsigned short* __restrict__ h1preb,
        float* __restrict__ partial1) {
    __shared__ short8 xls[64][16];   // 16 KB, col XOR-swizzled by (row&15)
    __shared__ float sred[4][128];
    int tid = threadIdx.x;
    int nbase = blockIdx.x * 64;
    const short8* h8 = (const short8*)xpb1;
    // -------- phase 1: gather 64 node-rows into LDS --------
    {
        int lane = tid & 15, grp = tid >> 4;
        for (int it = 0; it < 4; ++it) {
            int row = it * 16 + grp;
            int n = nbase + row; if (n >= N_NODES) n = N_NODES - 1;
            int beg = row_start[n], end = row_start[n + 1];
            short8 sv = h8[(size_t)n * 16 + lane];
            float a[8];
            #pragma unroll
            for (int j = 0; j < 8; ++j) a[j] = bf2f((unsigned short)sv[j]);
            int e = beg;
            for (; e + 3 < end; e += 4) {
                int s0 = csr_src[e], s1 = csr_src[e + 1], s2 = csr_src[e + 2], s3 = csr_src[e + 3];
                short8 v0 = h8[(size_t)s0 * 16 + lane];
                short8 v1 = h8[(size_t)s1 * 16 + lane];
                short8 v2 = h8[(size_t)s2 * 16 + lane];
                short8 v3 = h8[(size_t)s3 * 16 + lane];
                #pragma unroll
                for (int j = 0; j < 8; ++j)
                    a[j] += (bf2f((unsigned short)v0[j]) + bf2f((unsigned short)v1[j]))
                          + (bf2f((unsigned short)v2[j]) + bf2f((unsigned short)v3[j]));
            }
            for (; e < end; ++e) {
                short8 v0 = h8[(size_t)csr_src[e] * 16 + lane];
                #pragma unroll
                for (int j = 0; j < 8; ++j) a[j] += bf2f((unsigned short)v0[j]);
            }
            float s = deg_isqrt[n];
            short8 o;
            #pragma unroll
            for (int j = 0; j < 8; ++j) o[j] = (short)f2bf(a[j] * s);
            xls[row][lane ^ grp] = o;    // row&15 == grp
        }
    }
    __syncthreads();
    // -------- phase 2: expert MFMA from LDS --------
    int w = tid >> 6, l = tid & 63;
    int n0 = nbase + w * 16;
    int lo = l & 15, hi = l >> 4;
    int row = w * 16 + lo;               // row&15 == lo
    short8 a0 = xls[row][(hi)      ^ lo];
    short8 a1 = xls[row][(4 + hi)  ^ lo];
    short8 a2 = xls[row][(8 + hi)  ^ lo];
    short8 a3 = xls[row][(12 + hi) ^ lo];
    const short8* wp8 = (const short8*)wpack;
    float comb[4][4];
    #pragma unroll
    for (int t = 0; t < 4; ++t)
        #pragma unroll
        for (int r = 0; r < 4; ++r) comb[t][r] = 0.f;
    int nrow[4];
    #pragma unroll
    for (int r = 0; r < 4; ++r) {
        int n = n0 + hi * 4 + r;
        nrow[r] = (n < N_NODES) ? n : -1;
    }
    #pragma unroll
    for (int e = 0; e < NE; ++e) {
        float g_[4];
        #pragma unroll
        for (int r = 0; r < 4; ++r) g_[r] = (nrow[r] >= 0) ? gate[nrow[r] * 3 + e] : 0.f;
        #pragma unroll
        for (int t = 0; t < 4; ++t) {
            int fbase = (e * 16 + t * 4) * 64 + l;
            f32x4 acc = {0.f, 0.f, 0.f, 0.f};
            acc = __builtin_amdgcn_mfma_f32_16x16x32_bf16(a0, wp8[fbase      ], acc, 0, 0, 0);
            acc = __builtin_amdgcn_mfma_f32_16x16x32_bf16(a1, wp8[fbase +  64], acc, 0, 0, 0);
            acc = __builtin_amdgcn_mfma_f32_16x16x32_bf16(a2, wp8[fbase + 128], acc, 0, 0, 0);
            acc = __builtin_amdgcn_mfma_f32_16x16x32_bf16(a3, wp8[fbase + 192], acc, 0, 0, 0);
            float be = bexp[e * HDIM + t * 16 + lo];
            #pragma unroll
            for (int r = 0; r < 4; ++r) comb[t][r] = fmaf(g_[r], acc[r] + be, comb[t][r]);
        }
    }
    #pragma unroll
    for (int t = 0; t < 4; ++t) {
        float s = 0.f, q = 0.f;
        #pragma unroll
        for (int r = 0; r < 4; ++r) {
            if (nrow[r] >= 0) {
                float v = comb[t][r];
                h1preb[(size_t)nrow[r] * HDIM + t * 16 + lo] = f2bf(v);
                s += v; q = fmaf(v, v, q);
            }
        }
        s += __shfl_xor(s, 16, 64); s += __shfl_xor(s, 32, 64);
        q += __shfl_xor(q, 16, 64); q += __shfl_xor(q, 32, 64);
        if (hi == 0) {
            sred[w][t * 16 + lo] = s;
            sred[w][64 + t * 16 + lo] = q;
        }
    }
    __syncthreads();
    if (tid < 128)
        partial1[blockIdx.x * 128 + tid] =
            sred[0][tid] + sred[1][tid] + sred[2][tid] + sred[3][tid];
}

// ---------------- parallel column reduction: sums[c] = sum_k partial[k][c] ----------------
__global__ __launch_bounds__(256) void k_colred(const float* __restrict__ partial, int nblk,
                                                float* __restrict__ sums) {
    int c = blockIdx.x;          // 0..127
    int tid = threadIdx.x;
    float s = 0.f;
    for (int k = tid; k < nblk; k += 256)
        s += partial[(size_t)k * 128 + c];
    __shared__ float red[256];
    red[tid] = s;
    __syncthreads();
    #pragma unroll
    for (int off = 128; off >= 1; off >>= 1) {
        if (tid < off) red[tid] += red[tid + off];
        __syncthreads();
    }
    if (tid == 0) sums[c] = red[0];
}

// ---------------- bn1(inline)+relu fused into h1 @ W2 (bf16 in), epilogue *isq -> bf16 ----------------
__global__ __launch_bounds__(256) void k_w2(const unsigned short* __restrict__ h1preb,
        const float* __restrict__ sums, const float* __restrict__ bng, const float* __restrict__ bnb,
        const float* __restrict__ W2, const float* __restrict__ deg_isqrt,
        unsigned short* __restrict__ y) {
    __shared__ float scsh_s[128];
    __shared__ float4 hsd[64 * 16];  // 16 KB
    __shared__ float  wsd[64 * 64];  // 16 KB
    int tid = threadIdx.x;
    if (tid < 64) {
        float mu = sums[tid] * (1.0f / N_NODES);
        float var = sums[64 + tid] * (1.0f / N_NODES) - mu * mu;
        float rs = rsqrtf(var + BN_EPS);
        float sc = rs * bng[tid];
        scsh_s[tid] = sc;
        scsh_s[64 + tid] = bnb[tid] - mu * sc;
    }
    int nbase = blockIdx.x * 64;
    for (int i = tid; i < 64 * 16; i += 256) ((float4*)wsd)[i] = ((const float4*)W2)[i];
    __syncthreads();
    for (int i = tid; i < 64 * 8; i += 256) {
        int r = i >> 3, c8 = i & 7;
        int n = nbase + r; if (n >= N_NODES) n = N_NODES - 1;
        short8 v8 = ((const short8*)h1preb)[(size_t)n * 8 + c8];
        float vv[8];
        #pragma unroll
        for (int j = 0; j < 8; ++j) {
            int col = c8 * 8 + j;
            vv[j] = fmaxf(fmaf(bf2f((unsigned short)v8[j]), scsh_s[col], scsh_s[64 + col]), 0.f);
        }
        hsd[r * 16 + c8 * 2]     = make_float4(vv[0], vv[1], vv[2], vv[3]);
        hsd[r * 16 + c8 * 2 + 1] = make_float4(vv[4], vv[5], vv[6], vv[7]);
    }
    __syncthreads();
    int h = tid & 63, iq = tid >> 6;
    float acc[16];
    #pragma unroll
    for (int i = 0; i < 16; ++i) acc[i] = 0.f;
    for (int k4 = 0; k4 < 16; ++k4) {
        float w0 = wsd[(k4 * 4 + 0) * 64 + h];
        float w1 = wsd[(k4 * 4 + 1) * 64 + h];
        float w2v = wsd[(k4 * 4 + 2) * 64 + h];
        float w3 = wsd[(k4 * 4 + 3) * 64 + h];
        #pragma unroll
        for (int i = 0; i < 16; ++i) {
            float4 xv = hsd[(iq * 16 + i) * 16 + k4];
            acc[i] = fmaf(xv.x, w0, acc[i]);
            acc[i] = fmaf(xv.y, w1, acc[i]);
            acc[i] = fmaf(xv.z, w2v, acc[i]);
            acc[i] = fmaf(xv.w, w3, acc[i]);
        }
    }
    #pragma unroll
    for (int i = 0; i < 16; ++i) {
        int n = nbase + iq * 16 + i;
        if (n < N_NODES) y[(size_t)n * 64 + h] = f2bf(acc[i] * deg_isqrt[n]);
    }
}

// ---------------- stage-2 prop (bf16 in / bf16 out) + bn2 partials, 4-deep unroll ----------------
__global__ __launch_bounds__(256) void k_gsum_y(const int* __restrict__ csr_src,
        const int* __restrict__ row_start, const float* __restrict__ deg_isqrt,
        const unsigned short* __restrict__ hin, unsigned short* __restrict__ out,
        float* __restrict__ partial2) {
    int tid = threadIdx.x;
    int lane8 = tid & 7;
    int grp = tid >> 3;
    int n = blockIdx.x * 32 + grp;
    bool valid = n < N_NODES;
    int nn = valid ? n : N_NODES - 1;
    const short8* h8 = (const short8*)hin;
    int beg = row_start[nn], end = row_start[nn + 1];
    short8 sv = h8[(size_t)nn * 8 + lane8];
    float a[8];
    #pragma unroll
    for (int j = 0; j < 8; ++j) a[j] = bf2f((unsigned short)sv[j]);
    int e = beg;
    for (; e + 3 < end; e += 4) {
        int s0 = csr_src[e], s1 = csr_src[e + 1], s2 = csr_src[e + 2], s3 = csr_src[e + 3];
        short8 v0 = h8[(size_t)s0 * 8 + lane8];
        short8 v1 = h8[(size_t)s1 * 8 + lane8];
        short8 v2 = h8[(size_t)s2 * 8 + lane8];
        short8 v3 = h8[(size_t)s3 * 8 + lane8];
        #pragma unroll
        for (int j = 0; j < 8; ++j)
            a[j] += (bf2f((unsigned short)v0[j]) + bf2f((unsigned short)v1[j]))
                  + (bf2f((unsigned short)v2[j]) + bf2f((unsigned short)v3[j]));
    }
    for (; e < end; ++e) {
        short8 v0 = h8[(size_t)csr_src[e] * 8 + lane8];
        #pragma unroll
        for (int j = 0; j < 8; ++j) a[j] += bf2f((unsigned short)v0[j]);
    }
    float s = deg_isqrt[nn];
    float o[8];
    #pragma unroll
    for (int j = 0; j < 8; ++j) o[j] = a[j] * s;
    if (valid) {
        short8 ob;
        #pragma unroll
        for (int j = 0; j < 8; ++j) ob[j] = (short)f2bf(o[j]);
        ((short8*)out)[(size_t)n * 8 + lane8] = ob;
    }
    float ss[8], sq[8];
    #pragma unroll
    for (int j = 0; j < 8; ++j) {
        float v = valid ? o[j] : 0.f;
        ss[j] = v; sq[j] = v * v;
    }
    #pragma unroll
    for (int j = 0; j < 8; ++j) {
        ss[j] += __shfl_xor(ss[j], 8, 64);  sq[j] += __shfl_xor(sq[j], 8, 64);
        ss[j] += __shfl_xor(ss[j], 16, 64); sq[j] += __shfl_xor(sq[j], 16, 64);
        ss[j] += __shfl_xor(ss[j], 32, 64); sq[j] += __shfl_xor(sq[j], 32, 64);
    }
    __shared__ float sred[4][128];
    int wv = tid >> 6;
    if (((tid >> 3) & 7) == 0) {
        #pragma unroll
        for (int j = 0; j < 8; ++j) {
            sred[wv][lane8 * 8 + j] = ss[j];
            sred[wv][64 + lane8 * 8 + j] = sq[j];
        }
    }
    __syncthreads();
    if (tid < 128)
        partial2[blockIdx.x * 128 + tid] =
            sred[0][tid] + sred[1][tid] + sred[2][tid] + sred[3][tid];
}

// ---------------- bn2(inline) + relu + segmented pooling (bf16 in, 4 chunks/graph) ----------------
__global__ __launch_bounds__(256) void k_pool(const unsigned short* __restrict__ xp2b,
        const float* __restrict__ sums, const float* __restrict__ bng, const float* __restrict__ bnb,
        const int* __restrict__ gstart,
        float* __restrict__ psum, unsigned int* __restrict__ pmax) {
    __shared__ float scsh_s[128];
    int tid = threadIdx.x;
    if (tid < 64) {
        float mu = sums[tid] * (1.0f / N_NODES);
        float var = sums[64 + tid] * (1.0f / N_NODES) - mu * mu;
        float rs = rsqrtf(var + BN_EPS);
        float sc = rs * bng[tid];
        scsh_s[tid] = sc;
        scsh_s[64 + tid] = bnb[tid] - mu * sc;
    }
    __syncthreads();
    int g = blockIdx.x >> 2, ck = blockIdx.x & 3;
    int h = tid & 63, q = tid >> 6;
    int s0 = gstart[g], s1 = gstart[g + 1];
    int len = s1 - s0;
    int cbeg = s0 + (len * ck) / 4;
    int cend = s0 + (len * (ck + 1)) / 4;
    float sc = scsh_s[h], sh = scsh_s[64 + h];
    float ls = 0.f, lm = 0.f;
    int r = cbeg + q;
    for (; r + 12 < cend; r += 16) {
        float v0 = fmaxf(fmaf(bf2f(xp2b[(size_t)r * 64 + h]), sc, sh), 0.f);
        float v1 = fmaxf(fmaf(bf2f(xp2b[(size_t)(r + 4) * 64 + h]), sc, sh), 0.f);
        float v2 = fmaxf(fmaf(bf2f(xp2b[(size_t)(r + 8) * 64 + h]), sc, sh), 0.f);
        float v3 = fmaxf(fmaf(bf2f(xp2b[(size_t)(r + 12) * 64 + h]), sc, sh), 0.f);
        ls += (v0 + v1) + (v2 + v3);
        lm = fmaxf(fmaxf(fmaxf(lm, v0), fmaxf(v1, v2)), v3);
    }
    for (; r < cend; r += 4) {
        float v = fmaxf(fmaf(bf2f(xp2b[(size_t)r * 64 + h]), sc, sh), 0.f);
        ls += v; lm = fmaxf(lm, v);
    }
    __shared__ float red[2][4][64];
    red[0][q][h] = ls; red[1][q][h] = lm;
    __syncthreads();
    if (q == 0) {
        ls = red[0][0][h] + red[0][1][h] + red[0][2][h] + red[0][3][h];
        lm = fmaxf(fmaxf(red[1][0][h], red[1][1][h]), fmaxf(red[1][2][h], red[1][3][h]));
        atomicAdd(&psum[g * 64 + h], ls);
        atomicMax(&pmax[g * 64 + h], __float_as_uint(lm));
    }
}

// ---------------- classifier ----------------
__global__ void k_cls(const float* __restrict__ psum, const unsigned int* __restrict__ pmax,
                      const int* __restrict__ gstart, const float* __restrict__ Wc,
                      const float* __restrict__ bc, float* __restrict__ out) {
    int t = threadIdx.x;
    if (t >= NGRAPH * NC) return;
    int g = t / NC, c = t % NC;
    float cnt = (float)(gstart[g + 1] - gstart[g]);
    float invc = 1.f / fmaxf(cnt, 1.f);
    float acc = bc[c];
    #pragma unroll 8
    for (int j = 0; j < 64; ++j) {
        float s = psum[g * 64 + j];
        float mx = __uint_as_float(pmax[g * 64 + j]);
        acc = fmaf(s * invc, Wc[j * 3 + c], acc);
        acc = fmaf(mx, Wc[(64 + j) * 3 + c], acc);
        acc = fmaf(s, Wc[(128 + j) * 3 + c], acc);
    }
    out[g * NC + c] = acc;
}

extern "C" void kernel_launch(void* const* d_in, const int* in_sizes, int n_in,
                              void* d_out, int out_size, void* d_ws, size_t ws_size,
                              hipStream_t stream) {
    const float* x    = (const float*)d_in[0];
    const int*   ei   = (const int*)d_in[1];
    const int*   batch= (const int*)d_in[2];
    const float* Wexp = (const float*)d_in[3];
    const float* bexp = (const float*)d_in[4];
    const float* gW1  = (const float*)d_in[5];
    const float* gb1  = (const float*)d_in[6];
    const float* gW2  = (const float*)d_in[7];
    const float* gb2  = (const float*)d_in[8];
    const float* W2   = (const float*)d_in[9];
    // d_in[10] = b2: cancels inside bn2 (per-column constant shift)
    const float* bn1g = (const float*)d_in[11];
    const float* bn1b = (const float*)d_in[12];
    const float* bn2g = (const float*)d_in[13];
    const float* bn2b = (const float*)d_in[14];
    const float* clsW = (const float*)d_in[15];
    const float* clsb = (const float*)d_in[16];
    float* out = (float*)d_out;

    float* ws = (float*)d_ws;
    const size_t NN = N_NODES;
    float* deg_isqrt = ws;                                     // N
    float* gate      = ws + NN;                                // 3N
    unsigned short* xpb1   = (unsigned short*)(ws + 4 * NN);   // N*128 bf16
    unsigned short* h1preb = (unsigned short*)(ws + 132 * NN); // N*64 bf16
    unsigned short* ypb    = (unsigned short*)(ws + 164 * NN); // N*64 bf16
    unsigned short* xp2b   = (unsigned short*)(ws + 196 * NN); // N*64 bf16
    float* stats     = ws + 260 * NN;
    float* sums1 = stats + 256;                                // 128
    float* sums2 = stats + 384;                                // 128
    float* psum  = stats + 512;                                // G*64
    unsigned int* pmax = (unsigned int*)(stats + 512 + 4096);  // G*64
    int* gstart  = (int*)(stats + 512 + 8192);                 // G+1
    float* partial1 = stats + 16384;                           // NBLK_EXP*128
    float* partial2 = partial1 + 131072;                       // NBLK_GY*128
    int* row_start  = (int*)(partial2 + 262144);               // N+1 (+pad)
    int* bh         = row_start + NN + 8;                      // NBLK_A*256
    int* bucketbase = bh + NBLK_A * 256;                       // 257 (+pad)
    int* csr_src    = bucketbase + 264;                        // E
    int* pairs      = csr_src + N_EDGES;                       // E packed (src<<8|dst&255)
    unsigned short* wpack  = (unsigned short*)(pairs + N_EDGES);   // 24576 bf16
    unsigned short* gwpack = wpack + 24576;                        // 4096 bf16

    k_prep<<<14 + NBLK_A + 32, 256, 0, stream>>>(Wexp, gW1, batch, ei + N_EDGES,
                                                 wpack, gwpack, gstart, bh, psum);
    k_bscan<<<1, 256, 0, stream>>>(bh, bucketbase, row_start);
    k_bplace<<<NBLK_A, 256, 0, stream>>>(ei, bh, bucketbase, pairs);
    k_bfinal<<<NBUCK, 256, 0, stream>>>(pairs, bucketbase, row_start, deg_isqrt, csr_src);

    k_gateM<<<NBLK_EXP, 256, 0, stream>>>(x, deg_isqrt, gwpack, gb1, gW2, gb2, gate, xpb1);
    k_gx_exp<<<NBLK_EXP, 256, 0, stream>>>(csr_src, row_start, deg_isqrt, xpb1,
                                           wpack, bexp, gate, h1preb, partial1);
    k_colred<<<128, 256, 0, stream>>>(partial1, NBLK_EXP, sums1);
    k_w2<<<NBLK_EXP, 256, 0, stream>>>(h1preb, sums1, bn1g, bn1b, W2, deg_isqrt, ypb);
    k_gsum_y<<<NBLK_GY, 256, 0, stream>>>(csr_src, row_start, deg_isqrt, ypb, xp2b, partial2);
    k_colred<<<128, 256, 0, stream>>>(partial2, NBLK_GY, sums2);
    k_pool<<<NGRAPH * 4, 256, 0, stream>>>(xp2b, sums2, bn2g, bn2b, gstart, psum, pmax);
    k_cls<<<1, 256, 0, stream>>>(psum, pmax, gstart, clsW, clsb, out);
}

// Round 14
// 151.854 us; speedup vs baseline: 1.1774x; 1.1774x over previous
//
#include <hip/hip_runtime.h>

#define N_NODES 50000
#define N_EDGES 800000
#define F 128
#define HDIM 64
#define NE 3
#define NGRAPH 64
#define NC 3
#define BN_EPS 1e-5f
#define NBLK_A 200      // histogram/place blocks, 4000 edges each
#define NBUCK 196       // ceil(N_NODES/256) buckets of 256 nodes
#define NBLK_EXP 782    // ceil(N/64)
#define NBLK_GX 3125    // ceil(N/16)  -- gather+expert fused, 16 nodes/block
#define NBLK_GY 1563    // ceil(N/32)

typedef __attribute__((ext_vector_type(8))) short short8;
typedef __attribute__((ext_vector_type(4))) float f32x4;

__device__ inline unsigned short f2bf(float f) {
    unsigned int u = __float_as_uint(f);
    unsigned int r = (u + 0x7FFFu + ((u >> 16) & 1u)) >> 16;
    return (unsigned short)r;
}
__device__ inline float bf2f(unsigned short u) {
    return __uint_as_float(((unsigned int)u) << 16);
}

// ---------------- merged prep: W packs + gseg + bucket histogram + zero psum/pmax ----------------
__global__ __launch_bounds__(256) void k_prep(const float* __restrict__ Wexp,
        const float* __restrict__ gW1, const int* __restrict__ batch,
        const int* __restrict__ dst,
        unsigned short* __restrict__ wpack, unsigned short* __restrict__ gwpack,
        int* __restrict__ gstart, int* __restrict__ bh, float* __restrict__ zbase) {
    int b = blockIdx.x, tid = threadIdx.x;
    if (b < 12) {
        int t0 = b * 256 + tid;
        int f = t0 >> 6, l = t0 & 63;
        int e = f >> 4, t = (f >> 2) & 3, kk = f & 3;
        int h = t * 16 + (l & 15);
        int kbase = kk * 32 + (l >> 4) * 8;
        short8 o;
        #pragma unroll
        for (int j = 0; j < 8; ++j)
            o[j] = (short)f2bf(Wexp[e * (F * HDIM) + (kbase + j) * HDIM + h]);
        ((short8*)wpack)[f * 64 + l] = o;
    } else if (b == 12) {
        for (int t0 = tid; t0 < 8 * 64; t0 += 256) {
            int f = t0 >> 6, l = t0 & 63;
            int t = f >> 2, kk = f & 3;
            int h = t * 16 + (l & 15);
            int kbase = kk * 32 + (l >> 4) * 8;
            short8 o;
            #pragma unroll
            for (int j = 0; j < 8; ++j)
                o[j] = (short)f2bf(gW1[(kbase + j) * 32 + h]);
            ((short8*)gwpack)[f * 64 + l] = o;
        }
    } else if (b == 13) {
        int g = tid;
        if (g <= NGRAPH) {
            int lo = 0, hi = N_NODES;
            while (lo < hi) { int m = (lo + hi) >> 1; if (batch[m] < g) lo = m + 1; else hi = m; }
            gstart[g] = lo;
        }
    } else if (b < 14 + NBLK_A) {
        __shared__ int hist[256];
        hist[tid] = 0;
        __syncthreads();
        int base = (b - 14) * 4000;
        for (int i = tid; i < 4000; i += 256)
            atomicAdd(&hist[dst[base + i] >> 8], 1);
        __syncthreads();
        bh[(b - 14) * 256 + tid] = hist[tid];
    } else {
        int idx = (b - 14 - NBLK_A) * 256 + tid;   // zero psum(4096)+pmax(4096)
        if (idx < 8192) zbase[idx] = 0.f;
    }
}

// ---------------- CSR build, pass B: scan ----------------
__global__ __launch_bounds__(256) void k_bscan(int* __restrict__ bh, int* __restrict__ bucketbase,
                                               int* __restrict__ row_start) {
    int b = threadIdx.x;
    int sum = 0;
    #pragma unroll 4
    for (int k = 0; k < NBLK_A; ++k) {
        int v = bh[k * 256 + b];
        bh[k * 256 + b] = sum;
        sum += v;
    }
    int lane = b & 63, wid = b >> 6;
    __shared__ int wsums[4];
    int xsc = sum;
    #pragma unroll
    for (int off = 1; off < 64; off <<= 1) {
        int u = __shfl_up(xsc, off, 64);
        if (lane >= off) xsc += u;
    }
    if (lane == 63) wsums[wid] = xsc;
    __syncthreads();
    int woff = 0;
    for (int wq = 0; wq < wid; ++wq) woff += wsums[wq];
    int excl = woff + xsc - sum;
    bucketbase[b] = excl;
    if (b == 255) {
        bucketbase[256] = excl + sum;
        row_start[N_NODES] = excl + sum;
    }
}

// ---------------- CSR build, pass C: scatter packed (src<<8|dst&255) grouped by bucket ----------------
__global__ __launch_bounds__(256) void k_bplace(const int* __restrict__ ei, const int* __restrict__ bh,
        const int* __restrict__ bucketbase, int* __restrict__ pairs) {
    __shared__ int cur[256];
    int tid = threadIdx.x;
    cur[tid] = bucketbase[tid] + bh[blockIdx.x * 256 + tid];
    __syncthreads();
    int base = blockIdx.x * 4000;
    for (int i = tid; i < 4000; i += 256) {
        int e = base + i;
        int s = ei[e], d = ei[N_EDGES + e];
        int slot = atomicAdd(&cur[d >> 8], 1);
        pairs[slot] = (s << 8) | (d & 255);
    }
}

// ---------------- CSR build, pass D: per-bucket degrees, row_start, final placement ----------------
__global__ __launch_bounds__(256) void k_bfinal(const int* __restrict__ pairs,
        const int* __restrict__ bucketbase, int* __restrict__ row_start,
        float* __restrict__ deg_isqrt, int* __restrict__ csr_src) {
    __shared__ int deg[256];
    __shared__ int cur[256];
    __shared__ int wsums[4];
    int b = blockIdx.x, t = threadIdx.x;
    int beg = bucketbase[b], end = bucketbase[b + 1];
    deg[t] = 0;
    __syncthreads();
    for (int i = beg + t; i < end; i += 256)
        atomicAdd(&deg[pairs[i] & 255], 1);
    __syncthreads();
    int d = deg[t];
    int lane = t & 63, wid = t >> 6;
    int xsc = d;
    #pragma unroll
    for (int off = 1; off < 64; off <<= 1) {
        int u = __shfl_up(xsc, off, 64);
        if (lane >= off) xsc += u;
    }
    if (lane == 63) wsums[wid] = xsc;
    __syncthreads();
    int woff = 0;
    for (int wq = 0; wq < wid; ++wq) woff += wsums[wq];
    int rs = beg + woff + xsc - d;
    int node = b * 256 + t;
    if (node < N_NODES) {
        row_start[node] = rs;
        deg_isqrt[node] = rsqrtf((float)d + 1.0f);
    }
    cur[t] = rs;
    __syncthreads();
    for (int i = beg + t; i < end; i += 256) {
        int p = pairs[i];
        int slot = atomicAdd(&cur[p & 255], 1);
        csr_src[slot] = p >> 8;
    }
}

// ---------------- gate via MFMA + x' = x*isq bf16 side-output ----------------
__global__ __launch_bounds__(256) void k_gateM(const float* __restrict__ x,
        const float* __restrict__ deg_isqrt, const unsigned short* __restrict__ gwpack,
        const float* __restrict__ gb1, const float* __restrict__ gW2,
        const float* __restrict__ gb2, float* __restrict__ gate,
        unsigned short* __restrict__ xpb1) {
    int tid = threadIdx.x;
    int w = tid >> 6, l = tid & 63;
    int lo = l & 15, hi = l >> 4;
    int n0 = blockIdx.x * 64 + w * 16;
    int nlo = n0 + lo;
    bool vrow = nlo < N_NODES;
    int arow = vrow ? nlo : N_NODES - 1;
    float si = deg_isqrt[arow];
    short8 a[4];
    #pragma unroll
    for (int kk = 0; kk < 4; ++kk) {
        int c4 = (kk * 32 + hi * 8) >> 2;
        float4 v0 = ((const float4*)x)[(size_t)arow * 32 + c4];
        float4 v1 = ((const float4*)x)[(size_t)arow * 32 + c4 + 1];
        short8 t8;
        t8[0] = (short)f2bf(v0.x); t8[1] = (short)f2bf(v0.y);
        t8[2] = (short)f2bf(v0.z); t8[3] = (short)f2bf(v0.w);
        t8[4] = (short)f2bf(v1.x); t8[5] = (short)f2bf(v1.y);
        t8[6] = (short)f2bf(v1.z); t8[7] = (short)f2bf(v1.w);
        a[kk] = t8;
        if (vrow) {
            ushort4 o0, o1;
            o0.x = f2bf(v0.x * si); o0.y = f2bf(v0.y * si);
            o0.z = f2bf(v0.z * si); o0.w = f2bf(v0.w * si);
            o1.x = f2bf(v1.x * si); o1.y = f2bf(v1.y * si);
            o1.z = f2bf(v1.z * si); o1.w = f2bf(v1.w * si);
            ((ushort4*)xpb1)[(size_t)arow * 32 + c4]     = o0;
            ((ushort4*)xpb1)[(size_t)arow * 32 + c4 + 1] = o1;
        }
    }
    const short8* gw8 = (const short8*)gwpack;
    f32x4 acc0 = {0.f, 0.f, 0.f, 0.f}, acc1 = {0.f, 0.f, 0.f, 0.f};
    #pragma unroll
    for (int kk = 0; kk < 4; ++kk) {
        acc0 = __builtin_amdgcn_mfma_f32_16x16x32_bf16(a[kk], gw8[kk * 64 + l], acc0, 0, 0, 0);
        acc1 = __builtin_amdgcn_mfma_f32_16x16x32_bf16(a[kk], gw8[(4 + kk) * 64 + l], acc1, 0, 0, 0);
    }
    float b1a = gb1[lo], b1b = gb1[16 + lo];
    float w20[3], w21[3];
    #pragma unroll
    for (int e = 0; e < 3; ++e) { w20[e] = gW2[lo * 3 + e]; w21[e] = gW2[(16 + lo) * 3 + e]; }
    float bb0 = gb2[0], bb1 = gb2[1], bb2 = gb2[2];
    #pragma unroll
    for (int r = 0; r < 4; ++r) {
        float h0 = fmaxf(acc0[r] + b1a, 0.f);
        float h1 = fmaxf(acc1[r] + b1b, 0.f);
        float le[3];
        #pragma unroll
        for (int e = 0; e < 3; ++e) {
            float p = fmaf(h0, w20[e], h1 * w21[e]);
            p += __shfl_xor(p, 1, 64);
            p += __shfl_xor(p, 2, 64);
            p += __shfl_xor(p, 4, 64);
            p += __shfl_xor(p, 8, 64);
            le[e] = p;
        }
        le[0] += bb0; le[1] += bb1; le[2] += bb2;
        float m = fmaxf(le[0], fmaxf(le[1], le[2]));
        float e0 = __expf(le[0] - m), e1 = __expf(le[1] - m), e2 = __expf(le[2] - m);
        float inv = 1.f / (e0 + e1 + e2);
        int n = n0 + hi * 4 + r;
        if (n < N_NODES && lo < 3) {
            float gg = (lo == 0) ? e0 * inv : (lo == 1 ? e1 * inv : e2 * inv);
            gate[n * 3 + lo] = gg;
        }
    }
}

// ---------------- MERGED v2: 16 nodes/block — gather (1 row/thread, full TLP) + expert split over waves ----------------
__global__ __launch_bounds__(256) void k_gx_exp(const int* __restrict__ csr_src,
        const int* __restrict__ row_start, const float* __restrict__ deg_isqrt,
        const unsigned short* __restrict__ xpb1,
        const unsigned short* __restrict__ wpack, const float* __restrict__ bexp,
        const float* __restrict__ gate, unsigned short* __restrict__ h1preb,
        float* __restrict__ partial1) {
    __shared__ short8 xls[16][16];   // 4 KB, col XOR-swizzled by row
    int tid = threadIdx.x;
    int nbase = blockIdx.x * 16;
    const short8* h8 = (const short8*)xpb1;
    // -------- phase 1: each thread gathers ONE (node,lane16) pair — same TLP as standalone gsum_x --------
    {
        int lane = tid & 15, row = tid >> 4;   // row 0..15
        int n = nbase + row; if (n >= N_NODES) n = N_NODES - 1;
        int beg = row_start[n], end = row_start[n + 1];
        short8 sv = h8[(size_t)n * 16 + lane];
        float a[8];
        #pragma unroll
        for (int j = 0; j < 8; ++j) a[j] = bf2f((unsigned short)sv[j]);
        int e = beg;
        for (; e + 3 < end; e += 4) {
            int s0 = csr_src[e], s1 = csr_src[e + 1], s2 = csr_src[e + 2], s3 = csr_src[e + 3];
            short8 v0 = h8[(size_t)s0 * 16 + lane];
            short8 v1 = h8[(size_t)s1 * 16 + lane];
            short8 v2 = h8[(size_t)s2 * 16 + lane];
            short8 v3 = h8[(size_t)s3 * 16 + lane];
            #pragma unroll
            for (int j = 0; j < 8; ++j)
                a[j] += (bf2f((unsigned short)v0[j]) + bf2f((unsigned short)v1[j]))
                      + (bf2f((unsigned short)v2[j]) + bf2f((unsigned short)v3[j]));
        }
        for (; e < end; ++e) {
            short8 v0 = h8[(size_t)csr_src[e] * 16 + lane];
            #pragma unroll
            for (int j = 0; j < 8; ++j) a[j] += bf2f((unsigned short)v0[j]);
        }
        float s = deg_isqrt[n];
        short8 o;
        #pragma unroll
        for (int j = 0; j < 8; ++j) o[j] = (short)f2bf(a[j] * s);
        xls[row][lane ^ row] = o;
    }
    __syncthreads();
    // -------- phase 2: expert MFMA; wave w owns h-tile t = w (16 output cols) --------
    int w = tid >> 6, l = tid & 63;
    int lo = l & 15, hi = l >> 4;
    short8 a0 = xls[lo][(hi)      ^ lo];
    short8 a1 = xls[lo][(4 + hi)  ^ lo];
    short8 a2 = xls[lo][(8 + hi)  ^ lo];
    short8 a3 = xls[lo][(12 + hi) ^ lo];
    const short8* wp8 = (const short8*)wpack;
    int nrow[4];
    #pragma unroll
    for (int r = 0; r < 4; ++r) {
        int n = nbase + hi * 4 + r;
        nrow[r] = (n < N_NODES) ? n : -1;
    }
    float comb[4];
    #pragma unroll
    for (int r = 0; r < 4; ++r) comb[r] = 0.f;
    #pragma unroll
    for (int e = 0; e < NE; ++e) {
        float g_[4];
        #pragma unroll
        for (int r = 0; r < 4; ++r) g_[r] = (nrow[r] >= 0) ? gate[nrow[r] * 3 + e] : 0.f;
        int fbase = (e * 16 + w * 4) * 64 + l;
        f32x4 acc = {0.f, 0.f, 0.f, 0.f};
        acc = __builtin_amdgcn_mfma_f32_16x16x32_bf16(a0, wp8[fbase      ], acc, 0, 0, 0);
        acc = __builtin_amdgcn_mfma_f32_16x16x32_bf16(a1, wp8[fbase +  64], acc, 0, 0, 0);
        acc = __builtin_amdgcn_mfma_f32_16x16x32_bf16(a2, wp8[fbase + 128], acc, 0, 0, 0);
        acc = __builtin_amdgcn_mfma_f32_16x16x32_bf16(a3, wp8[fbase + 192], acc, 0, 0, 0);
        float be = bexp[e * HDIM + w * 16 + lo];
        #pragma unroll
        for (int r = 0; r < 4; ++r) comb[r] = fmaf(g_[r], acc[r] + be, comb[r]);
    }
    float s = 0.f, q = 0.f;
    #pragma unroll
    for (int r = 0; r < 4; ++r) {
        if (nrow[r] >= 0) {
            float v = comb[r];
            h1preb[(size_t)nrow[r] * HDIM + w * 16 + lo] = f2bf(v);
            s += v; q = fmaf(v, v, q);
        }
    }
    s += __shfl_xor(s, 16, 64); s += __shfl_xor(s, 32, 64);
    q += __shfl_xor(q, 16, 64); q += __shfl_xor(q, 32, 64);
    if (hi == 0) {
        partial1[(size_t)blockIdx.x * 128 + w * 16 + lo] = s;
        partial1[(size_t)blockIdx.x * 128 + 64 + w * 16 + lo] = q;
    }
}

// ---------------- parallel column reduction: sums[c] = sum_k partial[k][c] ----------------
__global__ __launch_bounds__(256) void k_colred(const float* __restrict__ partial, int nblk,
                                                float* __restrict__ sums) {
    int c = blockIdx.x;          // 0..127
    int tid = threadIdx.x;
    float s = 0.f;
    for (int k = tid; k < nblk; k += 256)
        s += partial[(size_t)k * 128 + c];
    __shared__ float red[256];
    red[tid] = s;
    __syncthreads();
    #pragma unroll
    for (int off = 128; off >= 1; off >>= 1) {
        if (tid < off) red[tid] += red[tid + off];
        __syncthreads();
    }
    if (tid == 0) sums[c] = red[0];
}

// ---------------- bn1(inline)+relu fused into h1 @ W2 (bf16 in), epilogue *isq -> bf16 ----------------
__global__ __launch_bounds__(256) void k_w2(const unsigned short* __restrict__ h1preb,
        const float* __restrict__ sums, const float* __restrict__ bng, const float* __restrict__ bnb,
        const float* __restrict__ W2, const float* __restrict__ deg_isqrt,
        unsigned short* __restrict__ y) {
    __shared__ float scsh_s[128];
    __shared__ float4 hsd[64 * 16];  // 16 KB
    __shared__ float  wsd[64 * 64];  // 16 KB
    int tid = threadIdx.x;
    if (tid < 64) {
        float mu = sums[tid] * (1.0f / N_NODES);
        float var = sums[64 + tid] * (1.0f / N_NODES) - mu * mu;
        float rs = rsqrtf(var + BN_EPS);
        float sc = rs * bng[tid];
        scsh_s[tid] = sc;
        scsh_s[64 + tid] = bnb[tid] - mu * sc;
    }
    int nbase = blockIdx.x * 64;
    for (int i = tid; i < 64 * 16; i += 256) ((float4*)wsd)[i] = ((const float4*)W2)[i];
    __syncthreads();
    for (int i = tid; i < 64 * 8; i += 256) {
        int r = i >> 3, c8 = i & 7;
        int n = nbase + r; if (n >= N_NODES) n = N_NODES - 1;
        short8 v8 = ((const short8*)h1preb)[(size_t)n * 8 + c8];
        float vv[8];
        #pragma unroll
        for (int j = 0; j < 8; ++j) {
            int col = c8 * 8 + j;
            vv[j] = fmaxf(fmaf(bf2f((unsigned short)v8[j]), scsh_s[col], scsh_s[64 + col]), 0.f);
        }
        hsd[r * 16 + c8 * 2]     = make_float4(vv[0], vv[1], vv[2], vv[3]);
        hsd[r * 16 + c8 * 2 + 1] = make_float4(vv[4], vv[5], vv[6], vv[7]);
    }
    __syncthreads();
    int h = tid & 63, iq = tid >> 6;
    float acc[16];
    #pragma unroll
    for (int i = 0; i < 16; ++i) acc[i] = 0.f;
    for (int k4 = 0; k4 < 16; ++k4) {
        float w0 = wsd[(k4 * 4 + 0) * 64 + h];
        float w1 = wsd[(k4 * 4 + 1) * 64 + h];
        float w2v = wsd[(k4 * 4 + 2) * 64 + h];
        float w3 = wsd[(k4 * 4 + 3) * 64 + h];
        #pragma unroll
        for (int i = 0; i < 16; ++i) {
            float4 xv = hsd[(iq * 16 + i) * 16 + k4];
            acc[i] = fmaf(xv.x, w0, acc[i]);
            acc[i] = fmaf(xv.y, w1, acc[i]);
            acc[i] = fmaf(xv.z, w2v, acc[i]);
            acc[i] = fmaf(xv.w, w3, acc[i]);
        }
    }
    #pragma unroll
    for (int i = 0; i < 16; ++i) {
        int n = nbase + iq * 16 + i;
        if (n < N_NODES) y[(size_t)n * 64 + h] = f2bf(acc[i] * deg_isqrt[n]);
    }
}

// ---------------- stage-2 prop (bf16 in / bf16 out) + bn2 partials, 4-deep unroll ----------------
__global__ __launch_bounds__(256) void k_gsum_y(const int* __restrict__ csr_src,
        const int* __restrict__ row_start, const float* __restrict__ deg_isqrt,
        const unsigned short* __restrict__ hin, unsigned short* __restrict__ out,
        float* __restrict__ partial2) {
    int tid = threadIdx.x;
    int lane8 = tid & 7;
    int grp = tid >> 3;
    int n = blockIdx.x * 32 + grp;
    bool valid = n < N_NODES;
    int nn = valid ? n : N_NODES - 1;
    const short8* h8 = (const short8*)hin;
    int beg = row_start[nn], end = row_start[nn + 1];
    short8 sv = h8[(size_t)nn * 8 + lane8];
    float a[8];
    #pragma unroll
    for (int j = 0; j < 8; ++j) a[j] = bf2f((unsigned short)sv[j]);
    int e = beg;
    for (; e + 3 < end; e += 4) {
        int s0 = csr_src[e], s1 = csr_src[e + 1], s2 = csr_src[e + 2], s3 = csr_src[e + 3];
        short8 v0 = h8[(size_t)s0 * 8 + lane8];
        short8 v1 = h8[(size_t)s1 * 8 + lane8];
        short8 v2 = h8[(size_t)s2 * 8 + lane8];
        short8 v3 = h8[(size_t)s3 * 8 + lane8];
        #pragma unroll
        for (int j = 0; j < 8; ++j)
            a[j] += (bf2f((unsigned short)v0[j]) + bf2f((unsigned short)v1[j]))
                  + (bf2f((unsigned short)v2[j]) + bf2f((unsigned short)v3[j]));
    }
    for (; e < end; ++e) {
        short8 v0 = h8[(size_t)csr_src[e] * 8 + lane8];
        #pragma unroll
        for (int j = 0; j < 8; ++j) a[j] += bf2f((unsigned short)v0[j]);
    }
    float s = deg_isqrt[nn];
    float o[8];
    #pragma unroll
    for (int j = 0; j < 8; ++j) o[j] = a[j] * s;
    if (valid) {
        short8 ob;
        #pragma unroll
        for (int j = 0; j < 8; ++j) ob[j] = (short)f2bf(o[j]);
        ((short8*)out)[(size_t)n * 8 + lane8] = ob;
    }
    float ss[8], sq[8];
    #pragma unroll
    for (int j = 0; j < 8; ++j) {
        float v = valid ? o[j] : 0.f;
        ss[j] = v; sq[j] = v * v;
    }
    #pragma unroll
    for (int j = 0; j < 8; ++j) {
        ss[j] += __shfl_xor(ss[j], 8, 64);  sq[j] += __shfl_xor(sq[j], 8, 64);
        ss[j] += __shfl_xor(ss[j], 16, 64); sq[j] += __shfl_xor(sq[j], 16, 64);
        ss[j] += __shfl_xor(ss[j], 32, 64); sq[j] += __shfl_xor(sq[j], 32, 64);
    }
    __shared__ float sred[4][128];
    int wv = tid >> 6;
    if (((tid >> 3) & 7) == 0) {
        #pragma unroll
        for (int j = 0; j < 8; ++j) {
            sred[wv][lane8 * 8 + j] = ss[j];
            sred[wv][64 + lane8 * 8 + j] = sq[j];
        }
    }
    __syncthreads();
    if (tid < 128)
        partial2[blockIdx.x * 128 + tid] =
            sred[0][tid] + sred[1][tid] + sred[2][tid] + sred[3][tid];
}

// ---------------- bn2(inline) + relu + segmented pooling (bf16 in, 4 chunks/graph) ----------------
__global__ __launch_bounds__(256) void k_pool(const unsigned short* __restrict__ xp2b,
        const float* __restrict__ sums, const float* __restrict__ bng, const float* __restrict__ bnb,
        const int* __restrict__ gstart,
        float* __restrict__ psum, unsigned int* __restrict__ pmax) {
    __shared__ float scsh_s[128];
    int tid = threadIdx.x;
    if (tid < 64) {
        float mu = sums[tid] * (1.0f / N_NODES);
        float var = sums[64 + tid] * (1.0f / N_NODES) - mu * mu;
        float rs = rsqrtf(var + BN_EPS);
        float sc = rs * bng[tid];
        scsh_s[tid] = sc;
        scsh_s[64 + tid] = bnb[tid] - mu * sc;
    }
    __syncthreads();
    int g = blockIdx.x >> 2, ck = blockIdx.x & 3;
    int h = tid & 63, q = tid >> 6;
    int s0 = gstart[g], s1 = gstart[g + 1];
    int len = s1 - s0;
    int cbeg = s0 + (len * ck) / 4;
    int cend = s0 + (len * (ck + 1)) / 4;
    float sc = scsh_s[h], sh = scsh_s[64 + h];
    float ls = 0.f, lm = 0.f;
    int r = cbeg + q;
    for (; r + 12 < cend; r += 16) {
        float v0 = fmaxf(fmaf(bf2f(xp2b[(size_t)r * 64 + h]), sc, sh), 0.f);
        float v1 = fmaxf(fmaf(bf2f(xp2b[(size_t)(r + 4) * 64 + h]), sc, sh), 0.f);
        float v2 = fmaxf(fmaf(bf2f(xp2b[(size_t)(r + 8) * 64 + h]), sc, sh), 0.f);
        float v3 = fmaxf(fmaf(bf2f(xp2b[(size_t)(r + 12) * 64 + h]), sc, sh), 0.f);
        ls += (v0 + v1) + (v2 + v3);
        lm = fmaxf(fmaxf(fmaxf(lm, v0), fmaxf(v1, v2)), v3);
    }
    for (; r < cend; r += 4) {
        float v = fmaxf(fmaf(bf2f(xp2b[(size_t)r * 64 + h]), sc, sh), 0.f);
        ls += v; lm = fmaxf(lm, v);
    }
    __shared__ float red[2][4][64];
    red[0][q][h] = ls; red[1][q][h] = lm;
    __syncthreads();
    if (q == 0) {
        ls = red[0][0][h] + red[0][1][h] + red[0][2][h] + red[0][3][h];
        lm = fmaxf(fmaxf(red[1][0][h], red[1][1][h]), fmaxf(red[1][2][h], red[1][3][h]));
        atomicAdd(&psum[g * 64 + h], ls);
        atomicMax(&pmax[g * 64 + h], __float_as_uint(lm));
    }
}

// ---------------- classifier ----------------
__global__ void k_cls(const float* __restrict__ psum, const unsigned int* __restrict__ pmax,
                      const int* __restrict__ gstart, const float* __restrict__ Wc,
                      const float* __restrict__ bc, float* __restrict__ out) {
    int t = threadIdx.x;
    if (t >= NGRAPH * NC) return;
    int g = t / NC, c = t % NC;
    float cnt = (float)(gstart[g + 1] - gstart[g]);
    float invc = 1.f / fmaxf(cnt, 1.f);
    float acc = bc[c];
    #pragma unroll 8
    for (int j = 0; j < 64; ++j) {
        float s = psum[g * 64 + j];
        float mx = __uint_as_float(pmax[g * 64 + j]);
        acc = fmaf(s * invc, Wc[j * 3 + c], acc);
        acc = fmaf(mx, Wc[(64 + j) * 3 + c], acc);
        acc = fmaf(s, Wc[(128 + j) * 3 + c], acc);
    }
    out[g * NC + c] = acc;
}

extern "C" void kernel_launch(void* const* d_in, const int* in_sizes, int n_in,
                              void* d_out, int out_size, void* d_ws, size_t ws_size,
                              hipStream_t stream) {
    const float* x    = (const float*)d_in[0];
    const int*   ei   = (const int*)d_in[1];
    const int*   batch= (const int*)d_in[2];
    const float* Wexp = (const float*)d_in[3];
    const float* bexp = (const float*)d_in[4];
    const float* gW1  = (const float*)d_in[5];
    const float* gb1  = (const float*)d_in[6];
    const float* gW2  = (const float*)d_in[7];
    const float* gb2  = (const float*)d_in[8];
    const float* W2   = (const float*)d_in[9];
    // d_in[10] = b2: cancels inside bn2 (per-column constant shift)
    const float* bn1g = (const float*)d_in[11];
    const float* bn1b = (const float*)d_in[12];
    const float* bn2g = (const float*)d_in[13];
    const float* bn2b = (const float*)d_in[14];
    const float* clsW = (const float*)d_in[15];
    const float* clsb = (const float*)d_in[16];
    float* out = (float*)d_out;

    float* ws = (float*)d_ws;
    const size_t NN = N_NODES;
    float* deg_isqrt = ws;                                     // N
    float* gate      = ws + NN;                                // 3N
    unsigned short* xpb1   = (unsigned short*)(ws + 4 * NN);   // N*128 bf16
    unsigned short* h1preb = (unsigned short*)(ws + 132 * NN); // N*64 bf16
    unsigned short* ypb    = (unsigned short*)(ws + 164 * NN); // N*64 bf16
    unsigned short* xp2b   = (unsigned short*)(ws + 196 * NN); // N*64 bf16
    float* stats     = ws + 260 * NN;
    float* sums1 = stats + 256;                                // 128
    float* sums2 = stats + 384;                                // 128
    float* psum  = stats + 512;                                // G*64
    unsigned int* pmax = (unsigned int*)(stats + 512 + 4096);  // G*64
    int* gstart  = (int*)(stats + 512 + 8192);                 // G+1
    float* partial1 = stats + 16384;                           // NBLK_GX*128 = 400000
    float* partial2 = partial1 + 400000;                       // NBLK_GY*128 = 200064
    int* row_start  = (int*)(partial2 + 200064);               // N+1 (+pad)
    int* bh         = row_start + NN + 8;                      // NBLK_A*256
    int* bucketbase = bh + NBLK_A * 256;                       // 257 (+pad)
    int* csr_src    = bucketbase + 264;                        // E
    int* pairs      = csr_src + N_EDGES;                       // E packed (src<<8|dst&255)
    unsigned short* wpack  = (unsigned short*)(pairs + N_EDGES);   // 24576 bf16
    unsigned short* gwpack = wpack + 24576;                        // 4096 bf16

    k_prep<<<14 + NBLK_A + 32, 256, 0, stream>>>(Wexp, gW1, batch, ei + N_EDGES,
                                                 wpack, gwpack, gstart, bh, psum);
    k_bscan<<<1, 256, 0, stream>>>(bh, bucketbase, row_start);
    k_bplace<<<NBLK_A, 256, 0, stream>>>(ei, bh, bucketbase, pairs);
    k_bfinal<<<NBUCK, 256, 0, stream>>>(pairs, bucketbase, row_start, deg_isqrt, csr_src);

    k_gateM<<<NBLK_EXP, 256, 0, stream>>>(x, deg_isqrt, gwpack, gb1, gW2, gb2, gate, xpb1);
    k_gx_exp<<<NBLK_GX, 256, 0, stream>>>(csr_src, row_start, deg_isqrt, xpb1,
                                          wpack, bexp, gate, h1preb, partial1);
    k_colred<<<128, 256, 0, stream>>>(partial1, NBLK_GX, sums1);
    k_w2<<<NBLK_EXP, 256, 0, stream>>>(h1preb, sums1, bn1g, bn1b, W2, deg_isqrt, ypb);
    k_gsum_y<<<NBLK_GY, 256, 0, stream>>>(csr_src, row_start, deg_isqrt, ypb, xp2b, partial2);
    k_colred<<<128, 256, 0, stream>>>(partial2, NBLK_GY, sums2);
    k_pool<<<NGRAPH * 4, 256, 0, stream>>>(xp2b, sums2, bn2g, bn2b, gstart, psum, pmax);
    k_cls<<<1, 256, 0, stream>>>(psum, pmax, gstart, clsW, clsb, out);
}

// Round 15
// 141.118 us; speedup vs baseline: 1.2670x; 1.0761x over previous
//
#include <hip/hip_runtime.h>

#define N_NODES 50000
#define N_EDGES 800000
#define F 128
#define HDIM 64
#define NE 3
#define NGRAPH 64
#define NC 3
#define BN_EPS 1e-5f
#define NBLK_A 200      // histogram/place blocks, 4000 edges each
#define NBUCK 196       // ceil(N_NODES/256) buckets of 256 nodes
#define NBLK_EXP 782    // ceil(N/64)
#define NBLK_GX 3125    // ceil(N/16)  -- gather+expert fused, 16 nodes/block
#define NBLK_GY 1563    // ceil(N/32)

typedef __attribute__((ext_vector_type(8))) short short8;
typedef __attribute__((ext_vector_type(4))) float f32x4;

__device__ inline unsigned short f2bf(float f) {
    unsigned int u = __float_as_uint(f);
    unsigned int r = (u + 0x7FFFu + ((u >> 16) & 1u)) >> 16;
    return (unsigned short)r;
}
__device__ inline float bf2f(unsigned short u) {
    return __uint_as_float(((unsigned int)u) << 16);
}

// ---------------- merged prep: W packs + gseg + bucket histogram + zero psum/pmax ----------------
__global__ __launch_bounds__(256) void k_prep(const float* __restrict__ Wexp,
        const float* __restrict__ gW1, const int* __restrict__ batch,
        const int* __restrict__ dst,
        unsigned short* __restrict__ wpack, unsigned short* __restrict__ gwpack,
        int* __restrict__ gstart, int* __restrict__ bh, float* __restrict__ zbase) {
    int b = blockIdx.x, tid = threadIdx.x;
    if (b < 12) {
        int t0 = b * 256 + tid;
        int f = t0 >> 6, l = t0 & 63;
        int e = f >> 4, t = (f >> 2) & 3, kk = f & 3;
        int h = t * 16 + (l & 15);
        int kbase = kk * 32 + (l >> 4) * 8;
        short8 o;
        #pragma unroll
        for (int j = 0; j < 8; ++j)
            o[j] = (short)f2bf(Wexp[e * (F * HDIM) + (kbase + j) * HDIM + h]);
        ((short8*)wpack)[f * 64 + l] = o;
    } else if (b == 12) {
        for (int t0 = tid; t0 < 8 * 64; t0 += 256) {
            int f = t0 >> 6, l = t0 & 63;
            int t = f >> 2, kk = f & 3;
            int h = t * 16 + (l & 15);
            int kbase = kk * 32 + (l >> 4) * 8;
            short8 o;
            #pragma unroll
            for (int j = 0; j < 8; ++j)
                o[j] = (short)f2bf(gW1[(kbase + j) * 32 + h]);
            ((short8*)gwpack)[f * 64 + l] = o;
        }
    } else if (b == 13) {
        int g = tid;
        if (g <= NGRAPH) {
            int lo = 0, hi = N_NODES;
            while (lo < hi) { int m = (lo + hi) >> 1; if (batch[m] < g) lo = m + 1; else hi = m; }
            gstart[g] = lo;
        }
    } else if (b < 14 + NBLK_A) {
        __shared__ int hist[256];
        hist[tid] = 0;
        __syncthreads();
        int base = (b - 14) * 4000;
        for (int i = tid; i < 4000; i += 256)
            atomicAdd(&hist[dst[base + i] >> 8], 1);
        __syncthreads();
        bh[(b - 14) * 256 + tid] = hist[tid];
    } else {
        int idx = (b - 14 - NBLK_A) * 256 + tid;   // zero psum(4096)+pmax(4096)
        if (idx < 8192) zbase[idx] = 0.f;
    }
}

// ---------------- CSR build, pass B1: per-column (bucket) parallel scan over blocks ----------------
__global__ __launch_bounds__(256) void k_bscan1(int* __restrict__ bh, int* __restrict__ btot) {
    int b = blockIdx.x;          // bucket column 0..255
    int tid = threadIdx.x;
    int v = (tid < NBLK_A) ? bh[tid * 256 + b] : 0;
    int lane = tid & 63, wid = tid >> 6;
    __shared__ int wsums[4];
    int xsc = v;
    #pragma unroll
    for (int off = 1; off < 64; off <<= 1) {
        int u = __shfl_up(xsc, off, 64);
        if (lane >= off) xsc += u;
    }
    if (lane == 63) wsums[wid] = xsc;
    __syncthreads();
    int woff = 0;
    for (int wq = 0; wq < wid; ++wq) woff += wsums[wq];
    int excl = woff + xsc - v;
    if (tid < NBLK_A) bh[tid * 256 + b] = excl;
    if (tid == 255) btot[b] = woff + xsc;   // column total
}

// ---------------- CSR build, pass B2: scan column totals -> bucketbase ----------------
__global__ __launch_bounds__(256) void k_bscan2(const int* __restrict__ btot,
        int* __restrict__ bucketbase, int* __restrict__ row_start) {
    int b = threadIdx.x;
    int v = btot[b];
    int lane = b & 63, wid = b >> 6;
    __shared__ int wsums[4];
    int xsc = v;
    #pragma unroll
    for (int off = 1; off < 64; off <<= 1) {
        int u = __shfl_up(xsc, off, 64);
        if (lane >= off) xsc += u;
    }
    if (lane == 63) wsums[wid] = xsc;
    __syncthreads();
    int woff = 0;
    for (int wq = 0; wq < wid; ++wq) woff += wsums[wq];
    int excl = woff + xsc - v;
    bucketbase[b] = excl;
    if (b == 255) {
        bucketbase[256] = excl + v;
        row_start[N_NODES] = excl + v;
    }
}

// ---------------- CSR build, pass C: scatter packed (src<<8|dst&255) grouped by bucket ----------------
__global__ __launch_bounds__(256) void k_bplace(const int* __restrict__ ei, const int* __restrict__ bh,
        const int* __restrict__ bucketbase, int* __restrict__ pairs) {
    __shared__ int cur[256];
    int tid = threadIdx.x;
    cur[tid] = bucketbase[tid] + bh[blockIdx.x * 256 + tid];
    __syncthreads();
    int base = blockIdx.x * 4000;
    for (int i = tid; i < 4000; i += 256) {
        int e = base + i;
        int s = ei[e], d = ei[N_EDGES + e];
        int slot = atomicAdd(&cur[d >> 8], 1);
        pairs[slot] = (s << 8) | (d & 255);
    }
}

// ---------------- CSR build, pass D: per-bucket degrees, row_start, final placement ----------------
__global__ __launch_bounds__(256) void k_bfinal(const int* __restrict__ pairs,
        const int* __restrict__ bucketbase, int* __restrict__ row_start,
        float* __restrict__ deg_isqrt, int* __restrict__ csr_src) {
    __shared__ int deg[256];
    __shared__ int cur[256];
    __shared__ int wsums[4];
    int b = blockIdx.x, t = threadIdx.x;
    int beg = bucketbase[b], end = bucketbase[b + 1];
    deg[t] = 0;
    __syncthreads();
    for (int i = beg + t; i < end; i += 256)
        atomicAdd(&deg[pairs[i] & 255], 1);
    __syncthreads();
    int d = deg[t];
    int lane = t & 63, wid = t >> 6;
    int xsc = d;
    #pragma unroll
    for (int off = 1; off < 64; off <<= 1) {
        int u = __shfl_up(xsc, off, 64);
        if (lane >= off) xsc += u;
    }
    if (lane == 63) wsums[wid] = xsc;
    __syncthreads();
    int woff = 0;
    for (int wq = 0; wq < wid; ++wq) woff += wsums[wq];
    int rs = beg + woff + xsc - d;
    int node = b * 256 + t;
    if (node < N_NODES) {
        row_start[node] = rs;
        deg_isqrt[node] = rsqrtf((float)d + 1.0f);
    }
    cur[t] = rs;
    __syncthreads();
    for (int i = beg + t; i < end; i += 256) {
        int p = pairs[i];
        int slot = atomicAdd(&cur[p & 255], 1);
        csr_src[slot] = p >> 8;
    }
}

// ---------------- gate via MFMA + x' = x*isq bf16 side-output ----------------
__global__ __launch_bounds__(256) void k_gateM(const float* __restrict__ x,
        const float* __restrict__ deg_isqrt, const unsigned short* __restrict__ gwpack,
        const float* __restrict__ gb1, const float* __restrict__ gW2,
        const float* __restrict__ gb2, float* __restrict__ gate,
        unsigned short* __restrict__ xpb1) {
    int tid = threadIdx.x;
    int w = tid >> 6, l = tid & 63;
    int lo = l & 15, hi = l >> 4;
    int n0 = blockIdx.x * 64 + w * 16;
    int nlo = n0 + lo;
    bool vrow = nlo < N_NODES;
    int arow = vrow ? nlo : N_NODES - 1;
    float si = deg_isqrt[arow];
    short8 a[4];
    #pragma unroll
    for (int kk = 0; kk < 4; ++kk) {
        int c4 = (kk * 32 + hi * 8) >> 2;
        float4 v0 = ((const float4*)x)[(size_t)arow * 32 + c4];
        float4 v1 = ((const float4*)x)[(size_t)arow * 32 + c4 + 1];
        short8 t8;
        t8[0] = (short)f2bf(v0.x); t8[1] = (short)f2bf(v0.y);
        t8[2] = (short)f2bf(v0.z); t8[3] = (short)f2bf(v0.w);
        t8[4] = (short)f2bf(v1.x); t8[5] = (short)f2bf(v1.y);
        t8[6] = (short)f2bf(v1.z); t8[7] = (short)f2bf(v1.w);
        a[kk] = t8;
        if (vrow) {
            ushort4 o0, o1;
            o0.x = f2bf(v0.x * si); o0.y = f2bf(v0.y * si);
            o0.z = f2bf(v0.z * si); o0.w = f2bf(v0.w * si);
            o1.x = f2bf(v1.x * si); o1.y = f2bf(v1.y * si);
            o1.z = f2bf(v1.z * si); o1.w = f2bf(v1.w * si);
            ((ushort4*)xpb1)[(size_t)arow * 32 + c4]     = o0;
            ((ushort4*)xpb1)[(size_t)arow * 32 + c4 + 1] = o1;
        }
    }
    const short8* gw8 = (const short8*)gwpack;
    f32x4 acc0 = {0.f, 0.f, 0.f, 0.f}, acc1 = {0.f, 0.f, 0.f, 0.f};
    #pragma unroll
    for (int kk = 0; kk < 4; ++kk) {
        acc0 = __builtin_amdgcn_mfma_f32_16x16x32_bf16(a[kk], gw8[kk * 64 + l], acc0, 0, 0, 0);
        acc1 = __builtin_amdgcn_mfma_f32_16x16x32_bf16(a[kk], gw8[(4 + kk) * 64 + l], acc1, 0, 0, 0);
    }
    float b1a = gb1[lo], b1b = gb1[16 + lo];
    float w20[3], w21[3];
    #pragma unroll
    for (int e = 0; e < 3; ++e) { w20[e] = gW2[lo * 3 + e]; w21[e] = gW2[(16 + lo) * 3 + e]; }
    float bb0 = gb2[0], bb1 = gb2[1], bb2 = gb2[2];
    #pragma unroll
    for (int r = 0; r < 4; ++r) {
        float h0 = fmaxf(acc0[r] + b1a, 0.f);
        float h1 = fmaxf(acc1[r] + b1b, 0.f);
        float le[3];
        #pragma unroll
        for (int e = 0; e < 3; ++e) {
            float p = fmaf(h0, w20[e], h1 * w21[e]);
            p += __shfl_xor(p, 1, 64);
            p += __shfl_xor(p, 2, 64);
            p += __shfl_xor(p, 4, 64);
            p += __shfl_xor(p, 8, 64);
            le[e] = p;
        }
        le[0] += bb0; le[1] += bb1; le[2] += bb2;
        float m = fmaxf(le[0], fmaxf(le[1], le[2]));
        float e0 = __expf(le[0] - m), e1 = __expf(le[1] - m), e2 = __expf(le[2] - m);
        float inv = 1.f / (e0 + e1 + e2);
        int n = n0 + hi * 4 + r;
        if (n < N_NODES && lo < 3) {
            float gg = (lo == 0) ? e0 * inv : (lo == 1 ? e1 * inv : e2 * inv);
            gate[n * 3 + lo] = gg;
        }
    }
}

// ---------------- MERGED: 16 nodes/block — gather (1 row/thread) + expert split over waves ----------------
__global__ __launch_bounds__(256) void k_gx_exp(const int* __restrict__ csr_src,
        const int* __restrict__ row_start, const float* __restrict__ deg_isqrt,
        const unsigned short* __restrict__ xpb1,
        const unsigned short* __restrict__ wpack, const float* __restrict__ bexp,
        const float* __restrict__ gate, unsigned short* __restrict__ h1preb,
        float* __restrict__ partial1) {
    __shared__ short8 xls[16][16];   // 4 KB, col XOR-swizzled by row
    int tid = threadIdx.x;
    int nbase = blockIdx.x * 16;
    const short8* h8 = (const short8*)xpb1;
    {
        int lane = tid & 15, row = tid >> 4;   // row 0..15
        int n = nbase + row; if (n >= N_NODES) n = N_NODES - 1;
        int beg = row_start[n], end = row_start[n + 1];
        short8 sv = h8[(size_t)n * 16 + lane];
        float a[8];
        #pragma unroll
        for (int j = 0; j < 8; ++j) a[j] = bf2f((unsigned short)sv[j]);
        int e = beg;
        for (; e + 3 < end; e += 4) {
            int s0 = csr_src[e], s1 = csr_src[e + 1], s2 = csr_src[e + 2], s3 = csr_src[e + 3];
            short8 v0 = h8[(size_t)s0 * 16 + lane];
            short8 v1 = h8[(size_t)s1 * 16 + lane];
            short8 v2 = h8[(size_t)s2 * 16 + lane];
            short8 v3 = h8[(size_t)s3 * 16 + lane];
            #pragma unroll
            for (int j = 0; j < 8; ++j)
                a[j] += (bf2f((unsigned short)v0[j]) + bf2f((unsigned short)v1[j]))
                      + (bf2f((unsigned short)v2[j]) + bf2f((unsigned short)v3[j]));
        }
        for (; e < end; ++e) {
            short8 v0 = h8[(size_t)csr_src[e] * 16 + lane];
            #pragma unroll
            for (int j = 0; j < 8; ++j) a[j] += bf2f((unsigned short)v0[j]);
        }
        float s = deg_isqrt[n];
        short8 o;
        #pragma unroll
        for (int j = 0; j < 8; ++j) o[j] = (short)f2bf(a[j] * s);
        xls[row][lane ^ row] = o;
    }
    __syncthreads();
    int w = tid >> 6, l = tid & 63;
    int lo = l & 15, hi = l >> 4;
    short8 a0 = xls[lo][(hi)      ^ lo];
    short8 a1 = xls[lo][(4 + hi)  ^ lo];
    short8 a2 = xls[lo][(8 + hi)  ^ lo];
    short8 a3 = xls[lo][(12 + hi) ^ lo];
    const short8* wp8 = (const short8*)wpack;
    int nrow[4];
    #pragma unroll
    for (int r = 0; r < 4; ++r) {
        int n = nbase + hi * 4 + r;
        nrow[r] = (n < N_NODES) ? n : -1;
    }
    float comb[4];
    #pragma unroll
    for (int r = 0; r < 4; ++r) comb[r] = 0.f;
    #pragma unroll
    for (int e = 0; e < NE; ++e) {
        float g_[4];
        #pragma unroll
        for (int r = 0; r < 4; ++r) g_[r] = (nrow[r] >= 0) ? gate[nrow[r] * 3 + e] : 0.f;
        int fbase = (e * 16 + w * 4) * 64 + l;
        f32x4 acc = {0.f, 0.f, 0.f, 0.f};
        acc = __builtin_amdgcn_mfma_f32_16x16x32_bf16(a0, wp8[fbase      ], acc, 0, 0, 0);
        acc = __builtin_amdgcn_mfma_f32_16x16x32_bf16(a1, wp8[fbase +  64], acc, 0, 0, 0);
        acc = __builtin_amdgcn_mfma_f32_16x16x32_bf16(a2, wp8[fbase + 128], acc, 0, 0, 0);
        acc = __builtin_amdgcn_mfma_f32_16x16x32_bf16(a3, wp8[fbase + 192], acc, 0, 0, 0);
        float be = bexp[e * HDIM + w * 16 + lo];
        #pragma unroll
        for (int r = 0; r < 4; ++r) comb[r] = fmaf(g_[r], acc[r] + be, comb[r]);
    }
    float s = 0.f, q = 0.f;
    #pragma unroll
    for (int r = 0; r < 4; ++r) {
        if (nrow[r] >= 0) {
            float v = comb[r];
            h1preb[(size_t)nrow[r] * HDIM + w * 16 + lo] = f2bf(v);
            s += v; q = fmaf(v, v, q);
        }
    }
    s += __shfl_xor(s, 16, 64); s += __shfl_xor(s, 32, 64);
    q += __shfl_xor(q, 16, 64); q += __shfl_xor(q, 32, 64);
    if (hi == 0) {
        partial1[(size_t)blockIdx.x * 128 + w * 16 + lo] = s;
        partial1[(size_t)blockIdx.x * 128 + 64 + w * 16 + lo] = q;
    }
}

// ---------------- parallel column reduction: sums[c] = sum_k partial[k][c] ----------------
__global__ __launch_bounds__(256) void k_colred(const float* __restrict__ partial, int nblk,
                                                float* __restrict__ sums) {
    int c = blockIdx.x;          // 0..127
    int tid = threadIdx.x;
    float s = 0.f;
    for (int k = tid; k < nblk; k += 256)
        s += partial[(size_t)k * 128 + c];
    __shared__ float red[256];
    red[tid] = s;
    __syncthreads();
    #pragma unroll
    for (int off = 128; off >= 1; off >>= 1) {
        if (tid < off) red[tid] += red[tid + off];
        __syncthreads();
    }
    if (tid == 0) sums[c] = red[0];
}

// ---------------- bn1(inline)+relu fused into h1 @ W2 (bf16 in), epilogue *isq -> bf16 ----------------
__global__ __launch_bounds__(256) void k_w2(const unsigned short* __restrict__ h1preb,
        const float* __restrict__ sums, const float* __restrict__ bng, const float* __restrict__ bnb,
        const float* __restrict__ W2, const float* __restrict__ deg_isqrt,
        unsigned short* __restrict__ y) {
    __shared__ float scsh_s[128];
    __shared__ float4 hsd[64 * 16];  // 16 KB
    __shared__ float  wsd[64 * 64];  // 16 KB
    int tid = threadIdx.x;
    if (tid < 64) {
        float mu = sums[tid] * (1.0f / N_NODES);
        float var = sums[64 + tid] * (1.0f / N_NODES) - mu * mu;
        float rs = rsqrtf(var + BN_EPS);
        float sc = rs * bng[tid];
        scsh_s[tid] = sc;
        scsh_s[64 + tid] = bnb[tid] - mu * sc;
    }
    int nbase = blockIdx.x * 64;
    for (int i = tid; i < 64 * 16; i += 256) ((float4*)wsd)[i] = ((const float4*)W2)[i];
    __syncthreads();
    for (int i = tid; i < 64 * 8; i += 256) {
        int r = i >> 3, c8 = i & 7;
        int n = nbase + r; if (n >= N_NODES) n = N_NODES - 1;
        short8 v8 = ((const short8*)h1preb)[(size_t)n * 8 + c8];
        float vv[8];
        #pragma unroll
        for (int j = 0; j < 8; ++j) {
            int col = c8 * 8 + j;
            vv[j] = fmaxf(fmaf(bf2f((unsigned short)v8[j]), scsh_s[col], scsh_s[64 + col]), 0.f);
        }
        hsd[r * 16 + c8 * 2]     = make_float4(vv[0], vv[1], vv[2], vv[3]);
        hsd[r * 16 + c8 * 2 + 1] = make_float4(vv[4], vv[5], vv[6], vv[7]);
    }
    __syncthreads();
    int h = tid & 63, iq = tid >> 6;
    float acc[16];
    #pragma unroll
    for (int i = 0; i < 16; ++i) acc[i] = 0.f;
    for (int k4 = 0; k4 < 16; ++k4) {
        float w0 = wsd[(k4 * 4 + 0) * 64 + h];
        float w1 = wsd[(k4 * 4 + 1) * 64 + h];
        float w2v = wsd[(k4 * 4 + 2) * 64 + h];
        float w3 = wsd[(k4 * 4 + 3) * 64 + h];
        #pragma unroll
        for (int i = 0; i < 16; ++i) {
            float4 xv = hsd[(iq * 16 + i) * 16 + k4];
            acc[i] = fmaf(xv.x, w0, acc[i]);
            acc[i] = fmaf(xv.y, w1, acc[i]);
            acc[i] = fmaf(xv.z, w2v, acc[i]);
            acc[i] = fmaf(xv.w, w3, acc[i]);
        }
    }
    #pragma unroll
    for (int i = 0; i < 16; ++i) {
        int n = nbase + iq * 16 + i;
        if (n < N_NODES) y[(size_t)n * 64 + h] = f2bf(acc[i] * deg_isqrt[n]);
    }
}

// ---------------- stage-2 prop (bf16 in / bf16 out) + bn2 partials, 4-deep unroll ----------------
__global__ __launch_bounds__(256) void k_gsum_y(const int* __restrict__ csr_src,
        const int* __restrict__ row_start, const float* __restrict__ deg_isqrt,
        const unsigned short* __restrict__ hin, unsigned short* __restrict__ out,
        float* __restrict__ partial2) {
    int tid = threadIdx.x;
    int lane8 = tid & 7;
    int grp = tid >> 3;
    int n = blockIdx.x * 32 + grp;
    bool valid = n < N_NODES;
    int nn = valid ? n : N_NODES - 1;
    const short8* h8 = (const short8*)hin;
    int beg = row_start[nn], end = row_start[nn + 1];
    short8 sv = h8[(size_t)nn * 8 + lane8];
    float a[8];
    #pragma unroll
    for (int j = 0; j < 8; ++j) a[j] = bf2f((unsigned short)sv[j]);
    int e = beg;
    for (; e + 3 < end; e += 4) {
        int s0 = csr_src[e], s1 = csr_src[e + 1], s2 = csr_src[e + 2], s3 = csr_src[e + 3];
        short8 v0 = h8[(size_t)s0 * 8 + lane8];
        short8 v1 = h8[(size_t)s1 * 8 + lane8];
        short8 v2 = h8[(size_t)s2 * 8 + lane8];
        short8 v3 = h8[(size_t)s3 * 8 + lane8];
        #pragma unroll
        for (int j = 0; j < 8; ++j)
            a[j] += (bf2f((unsigned short)v0[j]) + bf2f((unsigned short)v1[j]))
                  + (bf2f((unsigned short)v2[j]) + bf2f((unsigned short)v3[j]));
    }
    for (; e < end; ++e) {
        short8 v0 = h8[(size_t)csr_src[e] * 8 + lane8];
        #pragma unroll
        for (int j = 0; j < 8; ++j) a[j] += bf2f((unsigned short)v0[j]);
    }
    float s = deg_isqrt[nn];
    float o[8];
    #pragma unroll
    for (int j = 0; j < 8; ++j) o[j] = a[j] * s;
    if (valid) {
        short8 ob;
        #pragma unroll
        for (int j = 0; j < 8; ++j) ob[j] = (short)f2bf(o[j]);
        ((short8*)out)[(size_t)n * 8 + lane8] = ob;
    }
    float ss[8], sq[8];
    #pragma unroll
    for (int j = 0; j < 8; ++j) {
        float v = valid ? o[j] : 0.f;
        ss[j] = v; sq[j] = v * v;
    }
    #pragma unroll
    for (int j = 0; j < 8; ++j) {
        ss[j] += __shfl_xor(ss[j], 8, 64);  sq[j] += __shfl_xor(sq[j], 8, 64);
        ss[j] += __shfl_xor(ss[j], 16, 64); sq[j] += __shfl_xor(sq[j], 16, 64);
        ss[j] += __shfl_xor(ss[j], 32, 64); sq[j] += __shfl_xor(sq[j], 32, 64);
    }
    __shared__ float sred[4][128];
    int wv = tid >> 6;
    if (((tid >> 3) & 7) == 0) {
        #pragma unroll
        for (int j = 0; j < 8; ++j) {
            sred[wv][lane8 * 8 + j] = ss[j];
            sred[wv][64 + lane8 * 8 + j] = sq[j];
        }
    }
    __syncthreads();
    if (tid < 128)
        partial2[blockIdx.x * 128 + tid] =
            sred[0][tid] + sred[1][tid] + sred[2][tid] + sred[3][tid];
}

// ---------------- bn2(inline) + relu + segmented pooling (bf16 in, 4 chunks/graph) ----------------
__global__ __launch_bounds__(256) void k_pool(const unsigned short* __restrict__ xp2b,
        const float* __restrict__ sums, const float* __restrict__ bng, const float* __restrict__ bnb,
        const int* __restrict__ gstart,
        float* __restrict__ psum, unsigned int* __restrict__ pmax) {
    __shared__ float scsh_s[128];
    int tid = threadIdx.x;
    if (tid < 64) {
        float mu = sums[tid] * (1.0f / N_NODES);
        float var = sums[64 + tid] * (1.0f / N_NODES) - mu * mu;
        float rs = rsqrtf(var + BN_EPS);
        float sc = rs * bng[tid];
        scsh_s[tid] = sc;
        scsh_s[64 + tid] = bnb[tid] - mu * sc;
    }
    __syncthreads();
    int g = blockIdx.x >> 2, ck = blockIdx.x & 3;
    int h = tid & 63, q = tid >> 6;
    int s0 = gstart[g], s1 = gstart[g + 1];
    int len = s1 - s0;
    int cbeg = s0 + (len * ck) / 4;
    int cend = s0 + (len * (ck + 1)) / 4;
    float sc = scsh_s[h], sh = scsh_s[64 + h];
    float ls = 0.f, lm = 0.f;
    int r = cbeg + q;
    for (; r + 12 < cend; r += 16) {
        float v0 = fmaxf(fmaf(bf2f(xp2b[(size_t)r * 64 + h]), sc, sh), 0.f);
        float v1 = fmaxf(fmaf(bf2f(xp2b[(size_t)(r + 4) * 64 + h]), sc, sh), 0.f);
        float v2 = fmaxf(fmaf(bf2f(xp2b[(size_t)(r + 8) * 64 + h]), sc, sh), 0.f);
        float v3 = fmaxf(fmaf(bf2f(xp2b[(size_t)(r + 12) * 64 + h]), sc, sh), 0.f);
        ls += (v0 + v1) + (v2 + v3);
        lm = fmaxf(fmaxf(fmaxf(lm, v0), fmaxf(v1, v2)), v3);
    }
    for (; r < cend; r += 4) {
        float v = fmaxf(fmaf(bf2f(xp2b[(size_t)r * 64 + h]), sc, sh), 0.f);
        ls += v; lm = fmaxf(lm, v);
    }
    __shared__ float red[2][4][64];
    red[0][q][h] = ls; red[1][q][h] = lm;
    __syncthreads();
    if (q == 0) {
        ls = red[0][0][h] + red[0][1][h] + red[0][2][h] + red[0][3][h];
        lm = fmaxf(fmaxf(red[1][0][h], red[1][1][h]), fmaxf(red[1][2][h], red[1][3][h]));
        atomicAdd(&psum[g * 64 + h], ls);
        atomicMax(&pmax[g * 64 + h], __float_as_uint(lm));
    }
}

// ---------------- classifier ----------------
__global__ void k_cls(const float* __restrict__ psum, const unsigned int* __restrict__ pmax,
                      const int* __restrict__ gstart, const float* __restrict__ Wc,
                      const float* __restrict__ bc, float* __restrict__ out) {
    int t = threadIdx.x;
    if (t >= NGRAPH * NC) return;
    int g = t / NC, c = t % NC;
    float cnt = (float)(gstart[g + 1] - gstart[g]);
    float invc = 1.f / fmaxf(cnt, 1.f);
    float acc = bc[c];
    #pragma unroll 8
    for (int j = 0; j < 64; ++j) {
        float s = psum[g * 64 + j];
        float mx = __uint_as_float(pmax[g * 64 + j]);
        acc = fmaf(s * invc, Wc[j * 3 + c], acc);
        acc = fmaf(mx, Wc[(64 + j) * 3 + c], acc);
        acc = fmaf(s, Wc[(128 + j) * 3 + c], acc);
    }
    out[g * NC + c] = acc;
}

extern "C" void kernel_launch(void* const* d_in, const int* in_sizes, int n_in,
                              void* d_out, int out_size, void* d_ws, size_t ws_size,
                              hipStream_t stream) {
    const float* x    = (const float*)d_in[0];
    const int*   ei   = (const int*)d_in[1];
    const int*   batch= (const int*)d_in[2];
    const float* Wexp = (const float*)d_in[3];
    const float* bexp = (const float*)d_in[4];
    const float* gW1  = (const float*)d_in[5];
    const float* gb1  = (const float*)d_in[6];
    const float* gW2  = (const float*)d_in[7];
    const float* gb2  = (const float*)d_in[8];
    const float* W2   = (const float*)d_in[9];
    // d_in[10] = b2: cancels inside bn2 (per-column constant shift)
    const float* bn1g = (const float*)d_in[11];
    const float* bn1b = (const float*)d_in[12];
    const float* bn2g = (const float*)d_in[13];
    const float* bn2b = (const float*)d_in[14];
    const float* clsW = (const float*)d_in[15];
    const float* clsb = (const float*)d_in[16];
    float* out = (float*)d_out;

    float* ws = (float*)d_ws;
    const size_t NN = N_NODES;
    float* deg_isqrt = ws;                                     // N
    float* gate      = ws + NN;                                // 3N
    unsigned short* xpb1   = (unsigned short*)(ws + 4 * NN);   // N*128 bf16
    unsigned short* h1preb = (unsigned short*)(ws + 132 * NN); // N*64 bf16
    unsigned short* ypb    = (unsigned short*)(ws + 164 * NN); // N*64 bf16
    unsigned short* xp2b   = (unsigned short*)(ws + 196 * NN); // N*64 bf16
    float* stats     = ws + 260 * NN;
    float* sums1 = stats + 256;                                // 128
    float* sums2 = stats + 384;                                // 128
    float* psum  = stats + 512;                                // G*64
    unsigned int* pmax = (unsigned int*)(stats + 512 + 4096);  // G*64
    int* gstart  = (int*)(stats + 512 + 8192);                 // G+1
    float* partial1 = stats + 16384;                           // NBLK_GX*128 = 400000
    float* partial2 = partial1 + 400000;                       // NBLK_GY*128 = 200064
    int* row_start  = (int*)(partial2 + 200064);               // N+1 (+pad)
    int* bh         = row_start + NN + 8;                      // NBLK_A*256
    int* btot       = bh + NBLK_A * 256;                       // 256
    int* bucketbase = btot + 256;                              // 257 (+pad)
    int* csr_src    = bucketbase + 264;                        // E
    int* pairs      = csr_src + N_EDGES;                       // E packed (src<<8|dst&255)
    unsigned short* wpack  = (unsigned short*)(pairs + N_EDGES);   // 24576 bf16
    unsigned short* gwpack = wpack + 24576;                        // 4096 bf16

    k_prep<<<14 + NBLK_A + 32, 256, 0, stream>>>(Wexp, gW1, batch, ei + N_EDGES,
                                                 wpack, gwpack, gstart, bh, psum);
    k_bscan1<<<256, 256, 0, stream>>>(bh, btot);
    k_bscan2<<<1, 256, 0, stream>>>(btot, bucketbase, row_start);
    k_bplace<<<NBLK_A, 256, 0, stream>>>(ei, bh, bucketbase, pairs);
    k_bfinal<<<NBUCK, 256, 0, stream>>>(pairs, bucketbase, row_start, deg_isqrt, csr_src);

    k_gateM<<<NBLK_EXP, 256, 0, stream>>>(x, deg_isqrt, gwpack, gb1, gW2, gb2, gate, xpb1);
    k_gx_exp<<<NBLK_GX, 256, 0, stream>>>(csr_src, row_start, deg_isqrt, xpb1,
                                          wpack, bexp, gate, h1preb, partial1);
    k_colred<<<128, 256, 0, stream>>>(partial1, NBLK_GX, sums1);
    k_w2<<<NBLK_EXP, 256, 0, stream>>>(h1preb, sums1, bn1g, bn1b, W2, deg_isqrt, ypb);
    k_gsum_y<<<NBLK_GY, 256, 0, stream>>>(csr_src, row_start, deg_isqrt, ypb, xp2b, partial2);
    k_colred<<<128, 256, 0, stream>>>(partial2, NBLK_GY, sums2);
    k_pool<<<NGRAPH * 4, 256, 0, stream>>>(xp2b, sums2, bn2g, bn2b, gstart, psum, pmax);
    k_cls<<<1, 256, 0, stream>>>(psum, pmax, gstart, clsW, clsb, out);
}

// Round 16
// 139.731 us; speedup vs baseline: 1.2796x; 1.0099x over previous
//
#include <hip/hip_runtime.h>

#define N_NODES 50000
#define N_EDGES 800000
#define F 128
#define HDIM 64
#define NE 3
#define NGRAPH 64
#define NC 3
#define BN_EPS 1e-5f
#define NBLK_A 200      // histogram/place blocks, 4000 edges each
#define NBUCK 196       // ceil(N_NODES/256) buckets of 256 nodes
#define NBLK_EXP 782    // ceil(N/64)
#define NBLK_GX 3125    // ceil(N/16)  -- gather+expert fused, 16 nodes/block
#define NBLK_GY 1563    // ceil(N/32)

typedef __attribute__((ext_vector_type(8))) short short8;
typedef __attribute__((ext_vector_type(4))) float f32x4;

__device__ inline unsigned short f2bf(float f) {
    unsigned int u = __float_as_uint(f);
    unsigned int r = (u + 0x7FFFu + ((u >> 16) & 1u)) >> 16;
    return (unsigned short)r;
}
__device__ inline float bf2f(unsigned short u) {
    return __uint_as_float(((unsigned int)u) << 16);
}

// in-block exclusive scan of 256 ints held one-per-thread; result via bb_s[0..256]
__device__ inline void block_scan256(int v, int* bb_s) {
    int tid = threadIdx.x;
    int lane = tid & 63, wid = tid >> 6;
    __shared__ int wsums_sc[4];
    int xsc = v;
    #pragma unroll
    for (int off = 1; off < 64; off <<= 1) {
        int u = __shfl_up(xsc, off, 64);
        if (lane >= off) xsc += u;
    }
    if (lane == 63) wsums_sc[wid] = xsc;
    __syncthreads();
    int woff = 0;
    for (int wq = 0; wq < wid; ++wq) woff += wsums_sc[wq];
    bb_s[tid] = woff + xsc - v;
    if (tid == 255) bb_s[256] = woff + xsc;
    __syncthreads();
}

// ---------------- merged prep: W packs + gseg + bucket histogram + zero psum/pmax ----------------
__global__ __launch_bounds__(256) void k_prep(const float* __restrict__ Wexp,
        const float* __restrict__ gW1, const int* __restrict__ batch,
        const int* __restrict__ dst,
        unsigned short* __restrict__ wpack, unsigned short* __restrict__ gwpack,
        int* __restrict__ gstart, int* __restrict__ bh, float* __restrict__ zbase,
        int* __restrict__ row_start) {
    int b = blockIdx.x, tid = threadIdx.x;
    if (b < 12) {
        int t0 = b * 256 + tid;
        int f = t0 >> 6, l = t0 & 63;
        int e = f >> 4, t = (f >> 2) & 3, kk = f & 3;
        int h = t * 16 + (l & 15);
        int kbase = kk * 32 + (l >> 4) * 8;
        short8 o;
        #pragma unroll
        for (int j = 0; j < 8; ++j)
            o[j] = (short)f2bf(Wexp[e * (F * HDIM) + (kbase + j) * HDIM + h]);
        ((short8*)wpack)[f * 64 + l] = o;
    } else if (b == 12) {
        for (int t0 = tid; t0 < 8 * 64; t0 += 256) {
            int f = t0 >> 6, l = t0 & 63;
            int t = f >> 2, kk = f & 3;
            int h = t * 16 + (l & 15);
            int kbase = kk * 32 + (l >> 4) * 8;
            short8 o;
            #pragma unroll
            for (int j = 0; j < 8; ++j)
                o[j] = (short)f2bf(gW1[(kbase + j) * 32 + h]);
            ((short8*)gwpack)[f * 64 + l] = o;
        }
    } else if (b == 13) {
        int g = tid;
        if (g <= NGRAPH) {
            int lo = 0, hi = N_NODES;
            while (lo < hi) { int m = (lo + hi) >> 1; if (batch[m] < g) lo = m + 1; else hi = m; }
            gstart[g] = lo;
        }
        if (tid == 65) row_start[N_NODES] = N_EDGES;
    } else if (b < 14 + NBLK_A) {
        __shared__ int hist[256];
        hist[tid] = 0;
        __syncthreads();
        int base = (b - 14) * 4000;
        for (int i = tid; i < 4000; i += 256)
            atomicAdd(&hist[dst[base + i] >> 8], 1);
        __syncthreads();
        bh[(b - 14) * 256 + tid] = hist[tid];
    } else {
        int idx = (b - 14 - NBLK_A) * 256 + tid;   // zero psum(4096)+pmax(4096)
        if (idx < 8192) zbase[idx] = 0.f;
    }
}

// ---------------- CSR build, pass B1: per-column (bucket) parallel scan over blocks ----------------
__global__ __launch_bounds__(256) void k_bscan1(int* __restrict__ bh, int* __restrict__ btot) {
    int b = blockIdx.x;          // bucket column 0..255
    int tid = threadIdx.x;
    int v = (tid < NBLK_A) ? bh[tid * 256 + b] : 0;
    int lane = tid & 63, wid = tid >> 6;
    __shared__ int wsums[4];
    int xsc = v;
    #pragma unroll
    for (int off = 1; off < 64; off <<= 1) {
        int u = __shfl_up(xsc, off, 64);
        if (lane >= off) xsc += u;
    }
    if (lane == 63) wsums[wid] = xsc;
    __syncthreads();
    int woff = 0;
    for (int wq = 0; wq < wid; ++wq) woff += wsums[wq];
    int excl = woff + xsc - v;
    if (tid < NBLK_A) bh[tid * 256 + b] = excl;
    if (tid == 255) btot[b] = woff + xsc;   // column total
}

// ---------------- CSR build, pass C: scatter packed (src<<8|dst&255); bucketbase recomputed in-block ----------------
__global__ __launch_bounds__(256) void k_bplace(const int* __restrict__ ei, const int* __restrict__ bh,
        const int* __restrict__ btot, int* __restrict__ pairs) {
    __shared__ int bb_s[257];
    __shared__ int cur[256];
    int tid = threadIdx.x;
    block_scan256(btot[tid], bb_s);
    cur[tid] = bb_s[tid] + bh[blockIdx.x * 256 + tid];
    __syncthreads();
    int base = blockIdx.x * 4000;
    for (int i = tid; i < 4000; i += 256) {
        int e = base + i;
        int s = ei[e], d = ei[N_EDGES + e];
        int slot = atomicAdd(&cur[d >> 8], 1);
        pairs[slot] = (s << 8) | (d & 255);
    }
}

// ---------------- CSR build, pass D: per-bucket degrees, row_start, final placement ----------------
__global__ __launch_bounds__(256) void k_bfinal(const int* __restrict__ pairs,
        const int* __restrict__ btot, int* __restrict__ row_start,
        float* __restrict__ deg_isqrt, int* __restrict__ csr_src) {
    __shared__ int bb_s[257];
    __shared__ int deg[256];
    __shared__ int cur[256];
    __shared__ int wsums[4];
    int b = blockIdx.x, t = threadIdx.x;
    block_scan256(btot[t], bb_s);
    int beg = bb_s[b], end = bb_s[b + 1];
    deg[t] = 0;
    __syncthreads();
    for (int i = beg + t; i < end; i += 256)
        atomicAdd(&deg[pairs[i] & 255], 1);
    __syncthreads();
    int d = deg[t];
    int lane = t & 63, wid = t >> 6;
    int xsc = d;
    #pragma unroll
    for (int off = 1; off < 64; off <<= 1) {
        int u = __shfl_up(xsc, off, 64);
        if (lane >= off) xsc += u;
    }
    if (lane == 63) wsums[wid] = xsc;
    __syncthreads();
    int woff = 0;
    for (int wq = 0; wq < wid; ++wq) woff += wsums[wq];
    int rs = beg + woff + xsc - d;
    int node = b * 256 + t;
    if (node < N_NODES) {
        row_start[node] = rs;
        deg_isqrt[node] = rsqrtf((float)d + 1.0f);
    }
    cur[t] = rs;
    __syncthreads();
    for (int i = beg + t; i < end; i += 256) {
        int p = pairs[i];
        int slot = atomicAdd(&cur[p & 255], 1);
        csr_src[slot] = p >> 8;
    }
}

// ---------------- gate via MFMA + x' = x*isq bf16 side-output ----------------
__global__ __launch_bounds__(256) void k_gateM(const float* __restrict__ x,
        const float* __restrict__ deg_isqrt, const unsigned short* __restrict__ gwpack,
        const float* __restrict__ gb1, const float* __restrict__ gW2,
        const float* __restrict__ gb2, float* __restrict__ gate,
        unsigned short* __restrict__ xpb1) {
    int tid = threadIdx.x;
    int w = tid >> 6, l = tid & 63;
    int lo = l & 15, hi = l >> 4;
    int n0 = blockIdx.x * 64 + w * 16;
    int nlo = n0 + lo;
    bool vrow = nlo < N_NODES;
    int arow = vrow ? nlo : N_NODES - 1;
    float si = deg_isqrt[arow];
    short8 a[4];
    #pragma unroll
    for (int kk = 0; kk < 4; ++kk) {
        int c4 = (kk * 32 + hi * 8) >> 2;
        float4 v0 = ((const float4*)x)[(size_t)arow * 32 + c4];
        float4 v1 = ((const float4*)x)[(size_t)arow * 32 + c4 + 1];
        short8 t8;
        t8[0] = (short)f2bf(v0.x); t8[1] = (short)f2bf(v0.y);
        t8[2] = (short)f2bf(v0.z); t8[3] = (short)f2bf(v0.w);
        t8[4] = (short)f2bf(v1.x); t8[5] = (short)f2bf(v1.y);
        t8[6] = (short)f2bf(v1.z); t8[7] = (short)f2bf(v1.w);
        a[kk] = t8;
        if (vrow) {
            ushort4 o0, o1;
            o0.x = f2bf(v0.x * si); o0.y = f2bf(v0.y * si);
            o0.z = f2bf(v0.z * si); o0.w = f2bf(v0.w * si);
            o1.x = f2bf(v1.x * si); o1.y = f2bf(v1.y * si);
            o1.z = f2bf(v1.z * si); o1.w = f2bf(v1.w * si);
            ((ushort4*)xpb1)[(size_t)arow * 32 + c4]     = o0;
            ((ushort4*)xpb1)[(size_t)arow * 32 + c4 + 1] = o1;
        }
    }
    const short8* gw8 = (const short8*)gwpack;
    f32x4 acc0 = {0.f, 0.f, 0.f, 0.f}, acc1 = {0.f, 0.f, 0.f, 0.f};
    #pragma unroll
    for (int kk = 0; kk < 4; ++kk) {
        acc0 = __builtin_amdgcn_mfma_f32_16x16x32_bf16(a[kk], gw8[kk * 64 + l], acc0, 0, 0, 0);
        acc1 = __builtin_amdgcn_mfma_f32_16x16x32_bf16(a[kk], gw8[(4 + kk) * 64 + l], acc1, 0, 0, 0);
    }
    float b1a = gb1[lo], b1b = gb1[16 + lo];
    float w20[3], w21[3];
    #pragma unroll
    for (int e = 0; e < 3; ++e) { w20[e] = gW2[lo * 3 + e]; w21[e] = gW2[(16 + lo) * 3 + e]; }
    float bb0 = gb2[0], bb1 = gb2[1], bb2 = gb2[2];
    #pragma unroll
    for (int r = 0; r < 4; ++r) {
        float h0 = fmaxf(acc0[r] + b1a, 0.f);
        float h1 = fmaxf(acc1[r] + b1b, 0.f);
        float le[3];
        #pragma unroll
        for (int e = 0; e < 3; ++e) {
            float p = fmaf(h0, w20[e], h1 * w21[e]);
            p += __shfl_xor(p, 1, 64);
            p += __shfl_xor(p, 2, 64);
            p += __shfl_xor(p, 4, 64);
            p += __shfl_xor(p, 8, 64);
            le[e] = p;
        }
        le[0] += bb0; le[1] += bb1; le[2] += bb2;
        float m = fmaxf(le[0], fmaxf(le[1], le[2]));
        float e0 = __expf(le[0] - m), e1 = __expf(le[1] - m), e2 = __expf(le[2] - m);
        float inv = 1.f / (e0 + e1 + e2);
        int n = n0 + hi * 4 + r;
        if (n < N_NODES && lo < 3) {
            float gg = (lo == 0) ? e0 * inv : (lo == 1 ? e1 * inv : e2 * inv);
            gate[n * 3 + lo] = gg;
        }
    }
}

// ---------------- MERGED: 16 nodes/block — gather (1 row/thread) + expert split over waves ----------------
__global__ __launch_bounds__(256) void k_gx_exp(const int* __restrict__ csr_src,
        const int* __restrict__ row_start, const float* __restrict__ deg_isqrt,
        const unsigned short* __restrict__ xpb1,
        const unsigned short* __restrict__ wpack, const float* __restrict__ bexp,
        const float* __restrict__ gate, unsigned short* __restrict__ h1preb,
        float* __restrict__ partial1) {
    __shared__ short8 xls[16][16];   // 4 KB, col XOR-swizzled by row
    int tid = threadIdx.x;
    int nbase = blockIdx.x * 16;
    const short8* h8 = (const short8*)xpb1;
    {
        int lane = tid & 15, row = tid >> 4;   // row 0..15
        int n = nbase + row; if (n >= N_NODES) n = N_NODES - 1;
        int beg = row_start[n], end = row_start[n + 1];
        short8 sv = h8[(size_t)n * 16 + lane];
        float a[8];
        #pragma unroll
        for (int j = 0; j < 8; ++j) a[j] = bf2f((unsigned short)sv[j]);
        int e = beg;
        for (; e + 3 < end; e += 4) {
            int s0 = csr_src[e], s1 = csr_src[e + 1], s2 = csr_src[e + 2], s3 = csr_src[e + 3];
            short8 v0 = h8[(size_t)s0 * 16 + lane];
            short8 v1 = h8[(size_t)s1 * 16 + lane];
            short8 v2 = h8[(size_t)s2 * 16 + lane];
            short8 v3 = h8[(size_t)s3 * 16 + lane];
            #pragma unroll
            for (int j = 0; j < 8; ++j)
                a[j] += (bf2f((unsigned short)v0[j]) + bf2f((unsigned short)v1[j]))
                      + (bf2f((unsigned short)v2[j]) + bf2f((unsigned short)v3[j]));
        }
        for (; e < end; ++e) {
            short8 v0 = h8[(size_t)csr_src[e] * 16 + lane];
            #pragma unroll
            for (int j = 0; j < 8; ++j) a[j] += bf2f((unsigned short)v0[j]);
        }
        float s = deg_isqrt[n];
        short8 o;
        #pragma unroll
        for (int j = 0; j < 8; ++j) o[j] = (short)f2bf(a[j] * s);
        xls[row][lane ^ row] = o;
    }
    __syncthreads();
    int w = tid >> 6, l = tid & 63;
    int lo = l & 15, hi = l >> 4;
    short8 a0 = xls[lo][(hi)      ^ lo];
    short8 a1 = xls[lo][(4 + hi)  ^ lo];
    short8 a2 = xls[lo][(8 + hi)  ^ lo];
    short8 a3 = xls[lo][(12 + hi) ^ lo];
    const short8* wp8 = (const short8*)wpack;
    int nrow[4];
    #pragma unroll
    for (int r = 0; r < 4; ++r) {
        int n = nbase + hi * 4 + r;
        nrow[r] = (n < N_NODES) ? n : -1;
    }
    float comb[4];
    #pragma unroll
    for (int r = 0; r < 4; ++r) comb[r] = 0.f;
    #pragma unroll
    for (int e = 0; e < NE; ++e) {
        float g_[4];
        #pragma unroll
        for (int r = 0; r < 4; ++r) g_[r] = (nrow[r] >= 0) ? gate[nrow[r] * 3 + e] : 0.f;
        int fbase = (e * 16 + w * 4) * 64 + l;
        f32x4 acc = {0.f, 0.f, 0.f, 0.f};
        acc = __builtin_amdgcn_mfma_f32_16x16x32_bf16(a0, wp8[fbase      ], acc, 0, 0, 0);
        acc = __builtin_amdgcn_mfma_f32_16x16x32_bf16(a1, wp8[fbase +  64], acc, 0, 0, 0);
        acc = __builtin_amdgcn_mfma_f32_16x16x32_bf16(a2, wp8[fbase + 128], acc, 0, 0, 0);
        acc = __builtin_amdgcn_mfma_f32_16x16x32_bf16(a3, wp8[fbase + 192], acc, 0, 0, 0);
        float be = bexp[e * HDIM + w * 16 + lo];
        #pragma unroll
        for (int r = 0; r < 4; ++r) comb[r] = fmaf(g_[r], acc[r] + be, comb[r]);
    }
    float s = 0.f, q = 0.f;
    #pragma unroll
    for (int r = 0; r < 4; ++r) {
        if (nrow[r] >= 0) {
            float v = comb[r];
            h1preb[(size_t)nrow[r] * HDIM + w * 16 + lo] = f2bf(v);
            s += v; q = fmaf(v, v, q);
        }
    }
    s += __shfl_xor(s, 16, 64); s += __shfl_xor(s, 32, 64);
    q += __shfl_xor(q, 16, 64); q += __shfl_xor(q, 32, 64);
    if (hi == 0) {
        partial1[(size_t)blockIdx.x * 128 + w * 16 + lo] = s;
        partial1[(size_t)blockIdx.x * 128 + 64 + w * 16 + lo] = q;
    }
}

// ---------------- parallel column reduction: sums[c] = sum_k partial[k][c] ----------------
__global__ __launch_bounds__(256) void k_colred(const float* __restrict__ partial, int nblk,
                                                float* __restrict__ sums) {
    int c = blockIdx.x;          // 0..127
    int tid = threadIdx.x;
    float s = 0.f;
    for (int k = tid; k < nblk; k += 256)
        s += partial[(size_t)k * 128 + c];
    __shared__ float red[256];
    red[tid] = s;
    __syncthreads();
    #pragma unroll
    for (int off = 128; off >= 1; off >>= 1) {
        if (tid < off) red[tid] += red[tid + off];
        __syncthreads();
    }
    if (tid == 0) sums[c] = red[0];
}

// ---------------- bn1(inline)+relu fused into h1 @ W2 (bf16 in), epilogue *isq -> bf16 ----------------
__global__ __launch_bounds__(256) void k_w2(const unsigned short* __restrict__ h1preb,
        const float* __restrict__ sums, const float* __restrict__ bng, const float* __restrict__ bnb,
        const float* __restrict__ W2, const float* __restrict__ deg_isqrt,
        unsigned short* __restrict__ y) {
    __shared__ float scsh_s[128];
    __shared__ float4 hsd[64 * 16];  // 16 KB
    __shared__ float  wsd[64 * 64];  // 16 KB
    int tid = threadIdx.x;
    if (tid < 64) {
        float mu = sums[tid] * (1.0f / N_NODES);
        float var = sums[64 + tid] * (1.0f / N_NODES) - mu * mu;
        float rs = rsqrtf(var + BN_EPS);
        float sc = rs * bng[tid];
        scsh_s[tid] = sc;
        scsh_s[64 + tid] = bnb[tid] - mu * sc;
    }
    int nbase = blockIdx.x * 64;
    for (int i = tid; i < 64 * 16; i += 256) ((float4*)wsd)[i] = ((const float4*)W2)[i];
    __syncthreads();
    for (int i = tid; i < 64 * 8; i += 256) {
        int r = i >> 3, c8 = i & 7;
        int n = nbase + r; if (n >= N_NODES) n = N_NODES - 1;
        short8 v8 = ((const short8*)h1preb)[(size_t)n * 8 + c8];
        float vv[8];
        #pragma unroll
        for (int j = 0; j < 8; ++j) {
            int col = c8 * 8 + j;
            vv[j] = fmaxf(fmaf(bf2f((unsigned short)v8[j]), scsh_s[col], scsh_s[64 + col]), 0.f);
        }
        hsd[r * 16 + c8 * 2]     = make_float4(vv[0], vv[1], vv[2], vv[3]);
        hsd[r * 16 + c8 * 2 + 1] = make_float4(vv[4], vv[5], vv[6], vv[7]);
    }
    __syncthreads();
    int h = tid & 63, iq = tid >> 6;
    float acc[16];
    #pragma unroll
    for (int i = 0; i < 16; ++i) acc[i] = 0.f;
    for (int k4 = 0; k4 < 16; ++k4) {
        float w0 = wsd[(k4 * 4 + 0) * 64 + h];
        float w1 = wsd[(k4 * 4 + 1) * 64 + h];
        float w2v = wsd[(k4 * 4 + 2) * 64 + h];
        float w3 = wsd[(k4 * 4 + 3) * 64 + h];
        #pragma unroll
        for (int i = 0; i < 16; ++i) {
            float4 xv = hsd[(iq * 16 + i) * 16 + k4];
            acc[i] = fmaf(xv.x, w0, acc[i]);
            acc[i] = fmaf(xv.y, w1, acc[i]);
            acc[i] = fmaf(xv.z, w2v, acc[i]);
            acc[i] = fmaf(xv.w, w3, acc[i]);
        }
    }
    #pragma unroll
    for (int i = 0; i < 16; ++i) {
        int n = nbase + iq * 16 + i;
        if (n < N_NODES) y[(size_t)n * 64 + h] = f2bf(acc[i] * deg_isqrt[n]);
    }
}

// ---------------- stage-2 prop (bf16 in / bf16 out) + bn2 partials, 4-deep unroll ----------------
__global__ __launch_bounds__(256) void k_gsum_y(const int* __restrict__ csr_src,
        const int* __restrict__ row_start, const float* __restrict__ deg_isqrt,
        const unsigned short* __restrict__ hin, unsigned short* __restrict__ out,
        float* __restrict__ partial2) {
    int tid = threadIdx.x;
    int lane8 = tid & 7;
    int grp = tid >> 3;
    int n = blockIdx.x * 32 + grp;
    bool valid = n < N_NODES;
    int nn = valid ? n : N_NODES - 1;
    const short8* h8 = (const short8*)hin;
    int beg = row_start[nn], end = row_start[nn + 1];
    short8 sv = h8[(size_t)nn * 8 + lane8];
    float a[8];
    #pragma unroll
    for (int j = 0; j < 8; ++j) a[j] = bf2f((unsigned short)sv[j]);
    int e = beg;
    for (; e + 3 < end; e += 4) {
        int s0 = csr_src[e], s1 = csr_src[e + 1], s2 = csr_src[e + 2], s3 = csr_src[e + 3];
        short8 v0 = h8[(size_t)s0 * 8 + lane8];
        short8 v1 = h8[(size_t)s1 * 8 + lane8];
        short8 v2 = h8[(size_t)s2 * 8 + lane8];
        short8 v3 = h8[(size_t)s3 * 8 + lane8];
        #pragma unroll
        for (int j = 0; j < 8; ++j)
            a[j] += (bf2f((unsigned short)v0[j]) + bf2f((unsigned short)v1[j]))
                  + (bf2f((unsigned short)v2[j]) + bf2f((unsigned short)v3[j]));
    }
    for (; e < end; ++e) {
        short8 v0 = h8[(size_t)csr_src[e] * 8 + lane8];
        #pragma unroll
        for (int j = 0; j < 8; ++j) a[j] += bf2f((unsigned short)v0[j]);
    }
    float s = deg_isqrt[nn];
    float o[8];
    #pragma unroll
    for (int j = 0; j < 8; ++j) o[j] = a[j] * s;
    if (valid) {
        short8 ob;
        #pragma unroll
        for (int j = 0; j < 8; ++j) ob[j] = (short)f2bf(o[j]);
        ((short8*)out)[(size_t)n * 8 + lane8] = ob;
    }
    float ss[8], sq[8];
    #pragma unroll
    for (int j = 0; j < 8; ++j) {
        float v = valid ? o[j] : 0.f;
        ss[j] = v; sq[j] = v * v;
    }
    #pragma unroll
    for (int j = 0; j < 8; ++j) {
        ss[j] += __shfl_xor(ss[j], 8, 64);  sq[j] += __shfl_xor(sq[j], 8, 64);
        ss[j] += __shfl_xor(ss[j], 16, 64); sq[j] += __shfl_xor(sq[j], 16, 64);
        ss[j] += __shfl_xor(ss[j], 32, 64); sq[j] += __shfl_xor(sq[j], 32, 64);
    }
    __shared__ float sred[4][128];
    int wv = tid >> 6;
    if (((tid >> 3) & 7) == 0) {
        #pragma unroll
        for (int j = 0; j < 8; ++j) {
            sred[wv][lane8 * 8 + j] = ss[j];
            sred[wv][64 + lane8 * 8 + j] = sq[j];
        }
    }
    __syncthreads();
    if (tid < 128)
        partial2[blockIdx.x * 128 + tid] =
            sred[0][tid] + sred[1][tid] + sred[2][tid] + sred[3][tid];
}

// ---------------- bn2(inline) + relu + segmented pooling (bf16 in, 4 chunks/graph) ----------------
__global__ __launch_bounds__(256) void k_pool(const unsigned short* __restrict__ xp2b,
        const float* __restrict__ sums, const float* __restrict__ bng, const float* __restrict__ bnb,
        const int* __restrict__ gstart,
        float* __restrict__ psum, unsigned int* __restrict__ pmax) {
    __shared__ float scsh_s[128];
    int tid = threadIdx.x;
    if (tid < 64) {
        float mu = sums[tid] * (1.0f / N_NODES);
        float var = sums[64 + tid] * (1.0f / N_NODES) - mu * mu;
        float rs = rsqrtf(var + BN_EPS);
        float sc = rs * bng[tid];
        scsh_s[tid] = sc;
        scsh_s[64 + tid] = bnb[tid] - mu * sc;
    }
    __syncthreads();
    int g = blockIdx.x >> 2, ck = blockIdx.x & 3;
    int h = tid & 63, q = tid >> 6;
    int s0 = gstart[g], s1 = gstart[g + 1];
    int len = s1 - s0;
    int cbeg = s0 + (len * ck) / 4;
    int cend = s0 + (len * (ck + 1)) / 4;
    float sc = scsh_s[h], sh = scsh_s[64 + h];
    float ls = 0.f, lm = 0.f;
    int r = cbeg + q;
    for (; r + 12 < cend; r += 16) {
        float v0 = fmaxf(fmaf(bf2f(xp2b[(size_t)r * 64 + h]), sc, sh), 0.f);
        float v1 = fmaxf(fmaf(bf2f(xp2b[(size_t)(r + 4) * 64 + h]), sc, sh), 0.f);
        float v2 = fmaxf(fmaf(bf2f(xp2b[(size_t)(r + 8) * 64 + h]), sc, sh), 0.f);
        float v3 = fmaxf(fmaf(bf2f(xp2b[(size_t)(r + 12) * 64 + h]), sc, sh), 0.f);
        ls += (v0 + v1) + (v2 + v3);
        lm = fmaxf(fmaxf(fmaxf(lm, v0), fmaxf(v1, v2)), v3);
    }
    for (; r < cend; r += 4) {
        float v = fmaxf(fmaf(bf2f(xp2b[(size_t)r * 64 + h]), sc, sh), 0.f);
        ls += v; lm = fmaxf(lm, v);
    }
    __shared__ float red[2][4][64];
    red[0][q][h] = ls; red[1][q][h] = lm;
    __syncthreads();
    if (q == 0) {
        ls = red[0][0][h] + red[0][1][h] + red[0][2][h] + red[0][3][h];
        lm = fmaxf(fmaxf(red[1][0][h], red[1][1][h]), fmaxf(red[1][2][h], red[1][3][h]));
        atomicAdd(&psum[g * 64 + h], ls);
        atomicMax(&pmax[g * 64 + h], __float_as_uint(lm));
    }
}

// ---------------- classifier ----------------
__global__ void k_cls(const float* __restrict__ psum, const unsigned int* __restrict__ pmax,
                      const int* __restrict__ gstart, const float* __restrict__ Wc,
                      const float* __restrict__ bc, float* __restrict__ out) {
    int t = threadIdx.x;
    if (t >= NGRAPH * NC) return;
    int g = t / NC, c = t % NC;
    float cnt = (float)(gstart[g + 1] - gstart[g]);
    float invc = 1.f / fmaxf(cnt, 1.f);
    float acc = bc[c];
    #pragma unroll 8
    for (int j = 0; j < 64; ++j) {
        float s = psum[g * 64 + j];
        float mx = __uint_as_float(pmax[g * 64 + j]);
        acc = fmaf(s * invc, Wc[j * 3 + c], acc);
        acc = fmaf(mx, Wc[(64 + j) * 3 + c], acc);
        acc = fmaf(s, Wc[(128 + j) * 3 + c], acc);
    }
    out[g * NC + c] = acc;
}

extern "C" void kernel_launch(void* const* d_in, const int* in_sizes, int n_in,
                              void* d_out, int out_size, void* d_ws, size_t ws_size,
                              hipStream_t stream) {
    const float* x    = (const float*)d_in[0];
    const int*   ei   = (const int*)d_in[1];
    const int*   batch= (const int*)d_in[2];
    const float* Wexp = (const float*)d_in[3];
    const float* bexp = (const float*)d_in[4];
    const float* gW1  = (const float*)d_in[5];
    const float* gb1  = (const float*)d_in[6];
    const float* gW2  = (const float*)d_in[7];
    const float* gb2  = (const float*)d_in[8];
    const float* W2   = (const float*)d_in[9];
    // d_in[10] = b2: cancels inside bn2 (per-column constant shift)
    const float* bn1g = (const float*)d_in[11];
    const float* bn1b = (const float*)d_in[12];
    const float* bn2g = (const float*)d_in[13];
    const float* bn2b = (const float*)d_in[14];
    const float* clsW = (const float*)d_in[15];
    const float* clsb = (const float*)d_in[16];
    float* out = (float*)d_out;

    float* ws = (float*)d_ws;
    const size_t NN = N_NODES;
    float* deg_isqrt = ws;                                     // N
    float* gate      = ws + NN;                                // 3N
    unsigned short* xpb1   = (unsigned short*)(ws + 4 * NN);   // N*128 bf16
    unsigned short* h1preb = (unsigned short*)(ws + 132 * NN); // N*64 bf16
    unsigned short* ypb    = (unsigned short*)(ws + 164 * NN); // N*64 bf16
    unsigned short* xp2b   = (unsigned short*)(ws + 196 * NN); // N*64 bf16
    float* stats     = ws + 260 * NN;
    float* sums1 = stats + 256;                                // 128
    float* sums2 = stats + 384;                                // 128
    float* psum  = stats + 512;                                // G*64
    unsigned int* pmax = (unsigned int*)(stats + 512 + 4096);  // G*64
    int* gstart  = (int*)(stats + 512 + 8192);                 // G+1
    float* partial1 = stats + 16384;                           // NBLK_GX*128 = 400000
    float* partial2 = partial1 + 400000;                       // NBLK_GY*128 = 200064
    int* row_start  = (int*)(partial2 + 200064);               // N+1 (+pad)
    int* bh         = row_start + NN + 8;                      // NBLK_A*256
    int* btot       = bh + NBLK_A * 256;                       // 256
    int* csr_src    = btot + 264;                              // E
    int* pairs      = csr_src + N_EDGES;                       // E packed (src<<8|dst&255)
    unsigned short* wpack  = (unsigned short*)(pairs + N_EDGES);   // 24576 bf16
    unsigned short* gwpack = wpack + 24576;                        // 4096 bf16

    k_prep<<<14 + NBLK_A + 32, 256, 0, stream>>>(Wexp, gW1, batch, ei + N_EDGES,
                                                 wpack, gwpack, gstart, bh, psum, row_start);
    k_bscan1<<<256, 256, 0, stream>>>(bh, btot);
    k_bplace<<<NBLK_A, 256, 0, stream>>>(ei, bh, btot, pairs);
    k_bfinal<<<NBUCK, 256, 0, stream>>>(pairs, btot, row_start, deg_isqrt, csr_src);

    k_gateM<<<NBLK_EXP, 256, 0, stream>>>(x, deg_isqrt, gwpack, gb1, gW2, gb2, gate, xpb1);
    k_gx_exp<<<NBLK_GX, 256, 0, stream>>>(csr_src, row_start, deg_isqrt, xpb1,
                                          wpack, bexp, gate, h1preb, partial1);
    k_colred<<<128, 256, 0, stream>>>(partial1, NBLK_GX, sums1);
    k_w2<<<NBLK_EXP, 256, 0, stream>>>(h1preb, sums1, bn1g, bn1b, W2, deg_isqrt, ypb);
    k_gsum_y<<<NBLK_GY, 256, 0, stream>>>(csr_src, row_start, deg_isqrt, ypb, xp2b, partial2);
    k_colred<<<128, 256, 0, stream>>>(partial2, NBLK_GY, sums2);
    k_pool<<<NGRAPH * 4, 256, 0, stream>>>(xp2b, sums2, bn2g, bn2b, gstart, psum, pmax);
    k_cls<<<1, 256, 0, stream>>>(psum, pmax, gstart, clsW, clsb, out);
}